// Round 16
// baseline (178.400 us; speedup 1.0000x reference)
//
#include <hip/hip_runtime.h>

#define B_ 2
#define N_ 256
#define C_ 128
#define H_ 8

typedef __attribute__((ext_vector_type(8))) short bf16x8;
typedef __attribute__((ext_vector_type(8))) unsigned short u16x8;
typedef __attribute__((ext_vector_type(4))) float f32x4;

__device__ __forceinline__ unsigned short f2bf(float f) {
  unsigned int u = __float_as_uint(f);
  unsigned int r = (u + 0x7FFFu + ((u >> 16) & 1u)) >> 16;
  return (unsigned short)r;
}
__device__ __forceinline__ float bf2f(unsigned short u) {
  return __uint_as_float(((unsigned int)u) << 16);
}

// A-fragment from XOR-swizzled bf16 LDS tile [rows][128 cols] (256 B/row)
__device__ __forceinline__ bf16x8 lds_afrag(const char* base, int row0, int k0, int lane) {
  int row = row0 + (lane & 15);
  int cb = (k0 + 8 * (lane >> 4)) * 2;
  int byte = row * 256 + ((((cb >> 4) ^ (row & 7))) << 4);
  return *(const bf16x8*)(base + byte);
}

__device__ __forceinline__ void lds_store4bf(char* base, int row, int cbyte,
                                             float a, float b, float c, float d) {
  int byte = row * 256 + ((((cbyte >> 4) ^ (row & 7))) << 4) + (cbyte & 15);
  ushort4 o4;
  o4.x = f2bf(a); o4.y = f2bf(b); o4.z = f2bf(c); o4.w = f2bf(d);
  *(ushort4*)(base + byte) = o4;
}

// frag-major weight fetch: wbase -> [cfi][ks][lane][8] bf16
__device__ __forceinline__ bf16x8 wb_frag(const unsigned short* wbase,
                                          int cfi, int ks, int lane) {
  return *(const bf16x8*)(wbase + (((cfi * 4 + ks) * 64) + lane) * 8);
}

// ---------------- K0: mask dtype detection (parallel) ----------------
__global__ __launch_bounds__(256) void k_maskpart(const unsigned int* __restrict__ m4,
                                                  int* __restrict__ part)
{
  __shared__ int red[4];
  const int tid = threadIdx.x;
  unsigned int v = m4[blockIdx.x * 256 + tid];
  int cnt = ((v & 0xFFu) != 0) + (((v >> 8) & 0xFFu) != 0) +
            (((v >> 16) & 0xFFu) != 0) + ((v >> 24) != 0);
  #pragma unroll
  for (int m = 1; m < 64; m <<= 1) cnt += __shfl_xor(cnt, m);
  if ((tid & 63) == 0) red[tid >> 6] = cnt;
  __syncthreads();
  if (tid == 0) part[blockIdx.x] = red[0] + red[1] + red[2] + red[3];
}

__global__ __launch_bounds__(128) void k_maskred(const int* __restrict__ part,
                                                 int* __restrict__ flag)
{
  const int tid = threadIdx.x;
  int v = part[tid];
  #pragma unroll
  for (int m = 1; m < 64; m <<= 1) v += __shfl_xor(v, m);
  __shared__ int red[2];
  if ((tid & 63) == 0) red[tid >> 6] = v;
  __syncthreads();
  if (tid == 0) *flag = ((red[0] + red[1]) > 7864) ? 1 : 0;  // 1 = uint8 layout
}

// ---------------- K0b: weight conversion to fragment-major bf16 ----------------
// wb layout: [0]=wv1 [1]=wv2 [2]=wo [3]=w1 [4]=w2 (16384 each), +5*16384: wa (2048)
__global__ __launch_bounds__(256) void k_wconv(
    const float* __restrict__ wv1, const float* __restrict__ wv2,
    const float* __restrict__ wo, const float* __restrict__ w1,
    const float* __restrict__ w2,
    const float* __restrict__ wa1, const float* __restrict__ wa2,
    unsigned short* __restrict__ wb)
{
  const int m = blockIdx.x;
  const int tid = threadIdx.x;
  const int l = tid & 63;
  if (m < 5) {
    const float* W = (m == 0) ? wv1 : (m == 1) ? wv2 : (m == 2) ? wo : (m == 3) ? w1 : w2;
    unsigned short* o = wb + m * 16384;
    const int sub = tid >> 6;
    #pragma unroll
    for (int q = 0; q < 8; ++q) {
      int f = q * 4 + sub;              // fragment 0..31 (cf = f>>2, ks = f&3)
      int cf = f >> 2, ks = f & 3;
      int row = cf * 16 + (l & 15);
      int k = ks * 32 + 8 * (l >> 4);
      const float* p = W + row * 128 + k;
      float4 x = *(const float4*)p, y = *(const float4*)(p + 4);
      u16x8 t;
      t[0] = f2bf(x.x); t[1] = f2bf(x.y); t[2] = f2bf(x.z); t[3] = f2bf(x.w);
      t[4] = f2bf(y.x); t[5] = f2bf(y.y); t[6] = f2bf(y.z); t[7] = f2bf(y.w);
      *(u16x8*)(o + (f * 64 + l) * 8) = t;
    }
  } else {
    unsigned short* o = wb + 5 * 16384;
    const int ks = tid >> 6;
    int r = l & 15;
    const float* ar = (r < 8) ? (wa1 + r * 128) : (wa2 + (r - 8) * 128);
    const float* p = ar + ks * 32 + 8 * (l >> 4);
    float4 x = *(const float4*)p, y = *(const float4*)(p + 4);
    u16x8 t;
    t[0] = f2bf(x.x); t[1] = f2bf(x.y); t[2] = f2bf(x.z); t[3] = f2bf(x.w);
    t[4] = f2bf(y.x); t[5] = f2bf(y.y); t[6] = f2bf(y.z); t[7] = f2bf(y.w);
    *(u16x8*)(o + (ks * 64 + l) * 8) = t;
  }
}

// ---------------- K1: fused projections via MFMA, 64-pos tile, 8 waves ----------------
__global__ __launch_bounds__(512) void k_proj_mfma(
    const float* __restrict__ h, const unsigned short* __restrict__ wb,
    float* __restrict__ a1, float* __restrict__ a2,
    unsigned short* __restrict__ v1, unsigned short* __restrict__ v2)
{
  __shared__ __align__(16) char lds[16384 + 17408];
  char* hb  = lds;                 // bf16 swizzled h tile [64][256B]
  char* st1 = lds + 16384;         // v1 stage [32][272B]
  char* st2 = lds + 16384 + 8704;  // v2 stage [32][272B]
  const int tid = threadIdx.x, lane = tid & 63, w = tid >> 6;
  const size_t pos0 = (size_t)blockIdx.x * 64;

  const unsigned short* wbv = wb + ((w < 4) ? 0 : 16384);
  const unsigned short* wba = wb + 5 * 16384;
  const int colbase = (w & 3) * 32;
  bf16x8 bfr[2][4];
  #pragma unroll
  for (int cf = 0; cf < 2; ++cf)
    #pragma unroll
    for (int ks = 0; ks < 4; ++ks)
      bfr[cf][ks] = wb_frag(wbv, (w & 3) * 2 + cf, ks, lane);

  bf16x8 af[4];
  if (w == 0) {
    #pragma unroll
    for (int ks = 0; ks < 4; ++ks)
      af[ks] = *(const bf16x8*)(wba + (ks * 64 + lane) * 8);
  }

  {
    const float4* hg4 = (const float4*)(h + pos0 * 128);
    #pragma unroll
    for (int q = 0; q < 4; ++q) {
      int f4i = q * 512 + tid;
      float4 x = hg4[f4i];
      lds_store4bf(hb, f4i >> 5, (f4i & 31) * 8, x.x, x.y, x.z, x.w);
    }
  }
  __syncthreads();

  const int lg = lane >> 4, lc = lane & 15;
  for (int p = 0; p < 2; ++p) {
    const int R = p * 32;
    f32x4 acc[2][2];
    #pragma unroll
    for (int rf = 0; rf < 2; ++rf)
      #pragma unroll
      for (int cf = 0; cf < 2; ++cf) acc[rf][cf] = (f32x4){0.f,0.f,0.f,0.f};
    f32x4 acca[2]; acca[0] = (f32x4){0.f,0.f,0.f,0.f}; acca[1] = acca[0];

    #pragma unroll
    for (int ks = 0; ks < 4; ++ks) {
      bf16x8 a0  = lds_afrag(hb, R,      ks * 32, lane);
      bf16x8 a1f = lds_afrag(hb, R + 16, ks * 32, lane);
      #pragma unroll
      for (int cf = 0; cf < 2; ++cf) {
        acc[0][cf] = __builtin_amdgcn_mfma_f32_16x16x32_bf16(a0,  bfr[cf][ks], acc[0][cf], 0, 0, 0);
        acc[1][cf] = __builtin_amdgcn_mfma_f32_16x16x32_bf16(a1f, bfr[cf][ks], acc[1][cf], 0, 0, 0);
      }
      if (w == 0) {
        acca[0] = __builtin_amdgcn_mfma_f32_16x16x32_bf16(a0,  af[ks], acca[0], 0, 0, 0);
        acca[1] = __builtin_amdgcn_mfma_f32_16x16x32_bf16(a1f, af[ks], acca[1], 0, 0, 0);
      }
    }

    if (p) __syncthreads();
    {
      char* st = (w < 4) ? st1 : st2;
      #pragma unroll
      for (int rf = 0; rf < 2; ++rf)
        #pragma unroll
        for (int cf = 0; cf < 2; ++cf)
          #pragma unroll
          for (int r = 0; r < 4; ++r) {
            int row = rf*16 + 4*lg + r;
            int col = colbase + cf*16 + lc;
            *(unsigned short*)(st + row*272 + col*2) = f2bf(acc[rf][cf][r]);
          }
    }
    if (w == 0) {
      #pragma unroll
      for (int rf = 0; rf < 2; ++rf)
        #pragma unroll
        for (int r = 0; r < 4; ++r) {
          size_t row = pos0 + R + rf*16 + 4*lg + r;
          float val = acca[rf][r];
          if (lc < 8) a1[row * 8 + lc] = val;
          else        a2[row * 8 + (lc - 8)] = val;
        }
    }
    __syncthreads();
    #pragma unroll
    for (int q = 0; q < 2; ++q) {
      int s = q * 512 + tid;
      int bsel = s >> 9, idx = s & 511;
      int row = idx >> 4, seg = idx & 15;
      int4 v = *(const int4*)((bsel ? st2 : st1) + row*272 + seg*16);
      unsigned short* dst = bsel ? v2 : v1;
      *(int4*)(dst + (pos0 + R + row)*128 + seg*8) = v;
    }
  }
}

// ---------------- K2: fused row maxes (rowmax1 for id<512, rowmax2 for id>=512) ----------------
__global__ __launch_bounds__(64) void k_rowmax(const float* __restrict__ a1,
                                               const float* __restrict__ a2,
                                               float* __restrict__ amax1,
                                               float* __restrict__ amax2)
{
  const int id = blockIdx.x;
  const int t = threadIdx.x;
  if (id < 512) {
    const int bi = id;
    const float* base = a1 + (size_t)bi * N_ * 8;
    float m = -1e30f;
    #pragma unroll 8
    for (int k = 0; k < 32; ++k) m = fmaxf(m, base[t + 64*k]);
    m = fmaxf(m, __shfl_xor(m, 8));
    m = fmaxf(m, __shfl_xor(m, 16));
    m = fmaxf(m, __shfl_xor(m, 32));
    if (t < 8) amax1[bi*8 + t] = m;
  } else {
    const int bj = id - 512;
    const int b = bj >> 8, j = bj & 255;
    const int hh = t & 7, igrp = t >> 3;
    float m = -1e30f;
    for (int k = 0; k < 32; ++k) {
      int i = igrp + 8*k;
      m = fmaxf(m, a2[((size_t)(b*N_ + i)*N_ + j)*8 + hh]);
    }
    m = fmaxf(m, __shfl_xor(m, 8));
    m = fmaxf(m, __shfl_xor(m, 16));
    m = fmaxf(m, __shfl_xor(m, 32));
    if (t < 8) amax2[bj*8 + t] = m;
  }
}

// ---------------- K3: exp (masked); e2 f32 natural; eb1 bf16 -> Abuf ch128+ ----------------
__global__ __launch_bounds__(256) void k_e(
    const void* __restrict__ maskraw, const int* __restrict__ modep,
    const float* __restrict__ a1, const float* __restrict__ a2,
    const float* __restrict__ am1, const float* __restrict__ am2,
    float* __restrict__ e2out, unsigned short* __restrict__ Abuf)
{
  __shared__ unsigned short eb[8 * 256];   // [h][p] bf16
  const int tid = threadIdx.x;
  const size_t pos0 = (size_t)blockIdx.x * 256;
  const size_t p = pos0 + tid;
  const int b = (int)(p >> 16), ij = (int)(p & 65535);
  const int i = ij >> 8, j = ij & 255;
  const int msk = modep[0] ? (int)((const unsigned char*)maskraw)[p]
                           : ((const int*)maskraw)[p];
  float4 x0 = *(const float4*)(a1 + p*8);
  float4 x1 = *(const float4*)(a1 + p*8 + 4);
  float4 m0 = *(const float4*)(am1 + ((size_t)(b*256 + i))*8);
  float4 m1 = *(const float4*)(am1 + ((size_t)(b*256 + i))*8 + 4);
  eb[0*256 + tid] = msk ? 0 : f2bf(__expf(x0.x - m0.x));
  eb[1*256 + tid] = msk ? 0 : f2bf(__expf(x0.y - m0.y));
  eb[2*256 + tid] = msk ? 0 : f2bf(__expf(x0.z - m0.z));
  eb[3*256 + tid] = msk ? 0 : f2bf(__expf(x0.w - m0.w));
  eb[4*256 + tid] = msk ? 0 : f2bf(__expf(x1.x - m1.x));
  eb[5*256 + tid] = msk ? 0 : f2bf(__expf(x1.y - m1.y));
  eb[6*256 + tid] = msk ? 0 : f2bf(__expf(x1.z - m1.z));
  eb[7*256 + tid] = msk ? 0 : f2bf(__expf(x1.w - m1.w));

  float4 y0 = *(const float4*)(a2 + p*8);
  float4 y1 = *(const float4*)(a2 + p*8 + 4);
  float4 n0 = *(const float4*)(am2 + ((size_t)(b*256 + j))*8);
  float4 n1 = *(const float4*)(am2 + ((size_t)(b*256 + j))*8 + 4);
  float4 o0, o1;
  o0.x = msk ? 0.f : __expf(y0.x - n0.x);
  o0.y = msk ? 0.f : __expf(y0.y - n0.y);
  o0.z = msk ? 0.f : __expf(y0.z - n0.z);
  o0.w = msk ? 0.f : __expf(y0.w - n0.w);
  o1.x = msk ? 0.f : __expf(y1.x - n1.x);
  o1.y = msk ? 0.f : __expf(y1.y - n1.y);
  o1.z = msk ? 0.f : __expf(y1.z - n1.z);
  o1.w = msk ? 0.f : __expf(y1.w - n1.w);
  *(float4*)(e2out + p*8) = o0;
  *(float4*)(e2out + p*8 + 4) = o1;

  __syncthreads();
  {
    int hh = tid >> 5, seg = tid & 31;
    int4 v = *(const int4*)((const char*)eb + hh*512 + seg*16);
    *(int4*)(Abuf + (((size_t)(b*136 + 128 + hh)) << 16) + (int)(pos0 & 65535) + seg*8) = v;
  }
}

// ---------------- K4a: pc1[c][i][l] = vb1[pos][c] * e1 (channel transpose) ----------------
__global__ __launch_bounds__(256) void k_prep1(
    const unsigned short* __restrict__ vb1, unsigned short* __restrict__ Abuf)
{
  __shared__ __align__(16) char lds[36864];  // xt [128][272B] + et [8][256B]
  char* xt = lds;
  unsigned short* et = (unsigned short*)(lds + 34816);
  const int tid = threadIdx.x;
  const size_t pos0 = (size_t)blockIdx.x * 128;
  const int b = (int)(pos0 >> 16);
  const int posl0 = (int)(pos0 & 65535);

  if (tid < 128) {
    int hh = tid >> 4, seg = tid & 15;
    int4 v = *(const int4*)(Abuf + (((size_t)(b*136 + 128 + hh)) << 16) + posl0 + seg*8);
    *(int4*)((char*)et + hh*256 + seg*16) = v;
  }
  #pragma unroll
  for (int q = 0; q < 8; ++q) {
    int s = q*256 + tid;
    int rec = s >> 4, g = s & 15;
    int4 v = *(const int4*)(vb1 + (pos0 + rec)*128 + g*8);
    *(int4*)(xt + rec*272 + g*16) = v;
  }
  __syncthreads();
  #pragma unroll
  for (int q = 0; q < 8; ++q) {
    int c = q*16 + (tid & 15);
    int pg = tid >> 4;
    int hh = c >> 4;
    u16x8 t;
    #pragma unroll
    for (int k = 0; k < 8; ++k) {
      int p = pg*8 + k;
      float xv = bf2f(*(const unsigned short*)(xt + p*272 + c*2));
      float ev = bf2f(et[hh*128 + p]);
      t[k] = f2bf(xv * ev);
    }
    *(int4*)(Abuf + (((size_t)(b*136 + c)) << 16) + posl0 + pg*8) = *(int4*)&t;
  }
}

// ---------------- K4b: pc2t[c][j][l] = vb2[(l,j)][c]*e2 ; eb2t[h][j][l] ----------------
// cw split across blockIdx.x: bx = lt*4 + cw  (grid 32 x 16 x 2)
__global__ __launch_bounds__(256) void k_prep2(
    const unsigned short* __restrict__ vb2, const float* __restrict__ e2,
    unsigned short* __restrict__ Bbuf)
{
  __shared__ __align__(16) char lds[49152];  // vt [512][80B] + et [512][16B]
  char* vt = lds;
  unsigned short* et = (unsigned short*)(lds + 40960);  // [rec][8 h] bf16
  const int tid = threadIdx.x;
  const int bx = blockIdx.x, jt = blockIdx.y, b = blockIdx.z;
  const int lt = bx >> 2, cw = bx & 3;
  const int l0 = lt*32, j0 = jt*16;

  #pragma unroll
  for (int q = 0; q < 4; ++q) {
    int s = q*256 + tid;
    int rec = s >> 1, hf = (s & 1)*4;
    int l = rec >> 4, j = rec & 15;
    size_t pos = ((size_t)b << 16) + (size_t)(l0 + l)*256 + (j0 + j);
    float4 ev = *(const float4*)(e2 + pos*8 + hf);
    ushort4 o; o.x = f2bf(ev.x); o.y = f2bf(ev.y); o.z = f2bf(ev.z); o.w = f2bf(ev.w);
    *(ushort4*)(et + rec*8 + hf) = o;
  }

  {
    #pragma unroll
    for (int q = 0; q < 8; ++q) {
      int s = q*256 + tid;
      int rec = s >> 2, g = s & 3;
      int l = rec >> 4, j = rec & 15;
      size_t pos = ((size_t)b << 16) + (size_t)(l0 + l)*256 + (j0 + j);
      int4 v = *(const int4*)(vb2 + pos*128 + cw*32 + g*8);
      *(int4*)(vt + rec*80 + g*16) = v;
    }
    __syncthreads();
    #pragma unroll
    for (int q = 0; q < 8; ++q) {
      int loff = tid & 3, j = (tid >> 2) & 15, cs = tid >> 6;
      int cl = q*4 + cs;
      int c = cw*32 + cl;
      int hh = c >> 4;
      u16x8 t;
      #pragma unroll
      for (int k = 0; k < 8; ++k) {
        int l = loff*8 + k;
        int rec = l*16 + j;
        float xv = bf2f(*(const unsigned short*)(vt + rec*80 + cl*2));
        float ev = bf2f(et[rec*8 + hh]);
        t[k] = f2bf(xv * ev);
      }
      *(int4*)(Bbuf + (((size_t)(b*136 + c)) << 16) + (size_t)(j0 + j)*256 + l0 + loff*8) = *(int4*)&t;
    }
  }
  if (cw == 0) {
    #pragma unroll
    for (int q = 0; q < 2; ++q) {
      int s = q*256 + tid;
      int loff = s & 3, j = (s >> 2) & 15, hh = s >> 6;
      u16x8 t;
      #pragma unroll
      for (int k = 0; k < 8; ++k) {
        int l = loff*8 + k;
        int rec = l*16 + j;
        t[k] = et[rec*8 + hh];
      }
      *(int4*)(Bbuf + (((size_t)(b*136 + 128 + hh)) << 16) + (size_t)(j0 + j)*256 + l0 + loff*8) = *(int4*)&t;
    }
  }
}

// ---------------- K5: batched 256^3 GEMM over 272 channels (tri + denom) ----------------
// XCD-aware block swizzle (proven r15): all 4 tiles of a channel on one XCD.
__global__ __launch_bounds__(256) void k_tri_mfma(
    const unsigned short* __restrict__ Ab, const unsigned short* __restrict__ Bb,
    unsigned short* __restrict__ outT)
{
  __shared__ __align__(16) char lds[34816];
  char* lA = lds;
  char* lB = lds + 10240;
  const int tid = threadIdx.x, lane = tid & 63, w = tid >> 6;
  const int bid = blockIdx.x + 2 * blockIdx.y + 4 * blockIdx.z;  // 0..1087
  const int xcd = bid & 7;
  const int slot = bid >> 3;                 // 0..135
  const int ch_all = xcd * 34 + (slot >> 2); // 0..271
  const int tile = slot & 3;
  const int jt = tile & 1, it = tile >> 1;
  const int b = ch_all / 136, ch = ch_all - b*136;
  const size_t mbase = ((size_t)(b*136 + ch)) << 16;
  const int i0 = it*128, j0 = jt*128;
  const int r4 = tid >> 2, g4 = tid & 3;

  const unsigned short* gA0 = Ab + mbase + (size_t)(i0 + r4)*256 + g4*8;
  const unsigned short* gA1 = gA0 + 64*256;
  const unsigned short* gB0 = Bb + mbase + (size_t)(j0 + r4)*256 + g4*8;
  const unsigned short* gB1 = gB0 + 64*256;
  char* sA0 = lA + r4*80 + g4*16;
  char* sA1 = sA0 + 64*80;
  char* sB0 = lB + r4*80 + g4*16;
  char* sB1 = sB0 + 64*80;

  const int wr = w >> 1, wc = w & 1;
  const char* fA = lA + (wr*64 + (lane & 15))*80 + (lane >> 4)*16;
  const char* fB = lB + (wc*64 + (lane & 15))*80 + (lane >> 4)*16;

  f32x4 acc[4][4];
  #pragma unroll
  for (int rf = 0; rf < 4; ++rf)
    #pragma unroll
    for (int cf = 0; cf < 4; ++cf) acc[rf][cf] = (f32x4){0.f,0.f,0.f,0.f};

  int4 ra0 = *(const int4*)gA0;
  int4 ra1 = *(const int4*)gA1;
  int4 rb0 = *(const int4*)gB0;
  int4 rb1 = *(const int4*)gB1;

  for (int ks = 0; ks < 8; ++ks) {
    __syncthreads();
    *(int4*)sA0 = ra0; *(int4*)sA1 = ra1;
    *(int4*)sB0 = rb0; *(int4*)sB1 = rb1;
    __syncthreads();
    if (ks < 7) {
      const int off = (ks + 1)*32;
      ra0 = *(const int4*)(gA0 + off);
      ra1 = *(const int4*)(gA1 + off);
      rb0 = *(const int4*)(gB0 + off);
      rb1 = *(const int4*)(gB1 + off);
    }
    bf16x8 af[4], bfv[4];
    #pragma unroll
    for (int rf = 0; rf < 4; ++rf) af[rf] = *(const bf16x8*)(fA + rf*16*80);
    #pragma unroll
    for (int cf = 0; cf < 4; ++cf) bfv[cf] = *(const bf16x8*)(fB + cf*16*80);
    #pragma unroll
    for (int rf = 0; rf < 4; ++rf)
      #pragma unroll
      for (int cf = 0; cf < 4; ++cf)
        acc[rf][cf] = __builtin_amdgcn_mfma_f32_16x16x32_bf16(af[rf], bfv[cf], acc[rf][cf], 0, 0, 0);
  }

  __syncthreads();
  #pragma unroll
  for (int rf = 0; rf < 4; ++rf)
    #pragma unroll
    for (int cf = 0; cf < 4; ++cf)
      #pragma unroll
      for (int r = 0; r < 4; ++r) {
        int il = wr*64 + rf*16 + 4*(lane >> 4) + r;
        int jl = wc*64 + cf*16 + (lane & 15);
        *(unsigned short*)(lds + il*272 + jl*2) = f2bf(acc[rf][cf][r]);
      }
  __syncthreads();
  #pragma unroll
  for (int q = 0; q < 8; ++q) {
    int row = q*16 + (tid >> 4), seg = tid & 15;
    int4 v = *(const int4*)(lds + row*272 + seg*16);
    *(int4*)(outT + mbase + (size_t)(i0 + row)*256 + j0 + seg*8) = v;
  }
}

// ---------------- K6: x = t/denom ; y = x@wo^T ; hn = bf16(LN1(h + y))
//                  Swapped-operand MFMA: D-row = w-col, D-col = x-row.
//                  Per-thread 4 regs = 4 consecutive cols at one row -> ushort4 store. ----------------
__global__ __launch_bounds__(512) void k_wo_ln_mfma(
    const unsigned short* __restrict__ tT, const unsigned short* __restrict__ wb,
    const float* __restrict__ h,
    const float* __restrict__ g1, const float* __restrict__ bb1,
    unsigned short* __restrict__ hn)
{
  __shared__ __align__(16) char xb[64 * 256];
  __shared__ __align__(16) char stb[64 * 272];   // bf16 stage [64][136]
  const int tid = threadIdx.x, lane = tid & 63, w = tid >> 6;
  const size_t pos0 = (size_t)blockIdx.x * 64;
  const int b = (int)(pos0 >> 16);
  const int posl0 = (int)(pos0 & 65535);
  const int rh = w >> 2, cq = w & 3;
  const int R = rh * 32;
  const int lg = lane >> 4, lc = lane & 15;

  // ---- stage-in: x = t/denom -> xb ----
  #pragma unroll
  for (int it2 = 0; it2 < 2; ++it2) {
    int c = it2*64 + (tid >> 3);
    int poff = (tid & 7)*8;
    u16x8 tv = *(const u16x8*)(tT + (((size_t)(b*136 + c)) << 16) + posl0 + poff);
    u16x8 dv = *(const u16x8*)(tT + (((size_t)(b*136 + 128 + (c >> 4))) << 16) + posl0 + poff);
    int cb = c*2;
    #pragma unroll
    for (int k = 0; k < 8; ++k) {
      float x = bf2f(tv[k]) / (bf2f(dv[k]) + 1e-6f);
      int p = poff + k;
      int byte = p*256 + ((((cb >> 4) ^ (p & 7))) << 4) + (cb & 15);
      *(unsigned short*)(xb + byte) = f2bf(x);
    }
  }
  __syncthreads();

  // ---- GEMM (swapped): y = x @ wo^T -> stb via ushort4 ----
  {
    const unsigned short* wbo = wb + 2 * 16384;
    f32x4 acc[2][2];          // [xhalf][cf]
    #pragma unroll
    for (int xh = 0; xh < 2; ++xh)
      #pragma unroll
      for (int cf = 0; cf < 2; ++cf) acc[xh][cf] = (f32x4){0.f,0.f,0.f,0.f};
    #pragma unroll
    for (int ks = 0; ks < 4; ++ks) {
      bf16x8 a0  = lds_afrag(xb, R,      ks * 32, lane);
      bf16x8 a1f = lds_afrag(xb, R + 16, ks * 32, lane);
      #pragma unroll
      for (int cf = 0; cf < 2; ++cf) {
        bf16x8 bf = wb_frag(wbo, cq * 2 + cf, ks, lane);
        acc[0][cf] = __builtin_amdgcn_mfma_f32_16x16x32_bf16(bf, a0,  acc[0][cf], 0, 0, 0);
        acc[1][cf] = __builtin_amdgcn_mfma_f32_16x16x32_bf16(bf, a1f, acc[1][cf], 0, 0, 0);
      }
    }
    #pragma unroll
    for (int xh = 0; xh < 2; ++xh)
      #pragma unroll
      for (int cf = 0; cf < 2; ++cf) {
        int row = R + xh*16 + lc;
        int colb = cq*32 + cf*16 + 4*lg;
        ushort4 o;
        o.x = f2bf(acc[xh][cf][0]); o.y = f2bf(acc[xh][cf][1]);
        o.z = f2bf(acc[xh][cf][2]); o.w = f2bf(acc[xh][cf][3]);
        *(ushort4*)(stb + row*272 + colb*2) = o;
      }
  }
  __syncthreads();

  // ---- LN1 epilogue: full-wave pattern (proven r6/r11/r13/r14/r15) ----
  const float ga = g1[lane], gb = g1[64 + lane];
  const float ba = bb1[lane], bbv = bb1[64 + lane];
  for (int rr = 0; rr < 8; ++rr) {
    int row = w * 8 + rr;
    float y0 = bf2f(*(const unsigned short*)(stb + row*272 + lane*2));
    float y1 = bf2f(*(const unsigned short*)(stb + row*272 + (64 + lane)*2));
    float r0 = h[(pos0 + row) * 128 + lane] + y0;
    float r1 = h[(pos0 + row) * 128 + 64 + lane] + y1;
    float s = r0 + r1, sq = r0*r0 + r1*r1;
    #pragma unroll
    for (int m = 1; m < 64; m <<= 1) { s += __shfl_xor(s, m); sq += __shfl_xor(sq, m); }
    float mu = s * (1.f/128.f);
    float var = sq * (1.f/128.f) - mu*mu;
    float rstd = rsqrtf(var + 1e-5f);
    hn[(pos0 + row) * 128 + lane]      = f2bf((r0 - mu) * rstd * ga + ba);
    hn[(pos0 + row) * 128 + 64 + lane] = f2bf((r1 - mu) * rstd * gb + bbv);
  }
}

// ---------------- K7: FFN(silu) + residual + LN2 -> out (swapped MFMA, vector stores) ----------------
__global__ __launch_bounds__(512) void k_ffn_ln_mfma(
    const unsigned short* __restrict__ hnp, const unsigned short* __restrict__ wb,
    const float* __restrict__ bias1, const float* __restrict__ bias2,
    const float* __restrict__ g2, const float* __restrict__ b2v,
    float* __restrict__ out)
{
  __shared__ __align__(16) char xb[64 * 256];       // x then u (bf16 swizzled)
  __shared__ __align__(16) char stb[64 * 272];      // bf16 stage [64][136]
  const int tid = threadIdx.x, lane = tid & 63, w = tid >> 6;
  const size_t pos0 = (size_t)blockIdx.x * 64;
  const int rh = w >> 2, cq = w & 3;
  const int R = rh * 32;
  const int lg = lane >> 4, lc = lane & 15;
  const unsigned short* wb1 = wb + 3 * 16384;
  const unsigned short* wb2 = wb + 4 * 16384;

  bf16x8 bf1[2][4];
  #pragma unroll
  for (int cf = 0; cf < 2; ++cf)
    #pragma unroll
    for (int ks = 0; ks < 4; ++ks)
      bf1[cf][ks] = wb_frag(wb1, cq * 2 + cf, ks, lane);

  #pragma unroll
  for (int q = 0; q < 2; ++q) {
    int s = q*512 + tid;
    int row = s >> 4, g = s & 15;
    int4 v = *(const int4*)(hnp + (pos0 + row)*128 + g*8);
    *(int4*)(xb + row*256 + (((g ^ (row & 7))) << 4)) = v;
  }
  __syncthreads();

  // ---- GEMM1 (swapped): acc[xh][cf], u = silu(acc + b1) -> xb via lds_store4bf ----
  f32x4 acc[2][2];
  #pragma unroll
  for (int xh = 0; xh < 2; ++xh)
    #pragma unroll
    for (int cf = 0; cf < 2; ++cf) acc[xh][cf] = (f32x4){0.f,0.f,0.f,0.f};

  #pragma unroll
  for (int ks = 0; ks < 4; ++ks) {
    bf16x8 a0  = lds_afrag(xb, R,      ks * 32, lane);
    bf16x8 a1f = lds_afrag(xb, R + 16, ks * 32, lane);
    #pragma unroll
    for (int cf = 0; cf < 2; ++cf) {
      acc[0][cf] = __builtin_amdgcn_mfma_f32_16x16x32_bf16(bf1[cf][ks], a0,  acc[0][cf], 0, 0, 0);
      acc[1][cf] = __builtin_amdgcn_mfma_f32_16x16x32_bf16(bf1[cf][ks], a1f, acc[1][cf], 0, 0, 0);
    }
  }
  __syncthreads();

  {
    #pragma unroll
    for (int xh = 0; xh < 2; ++xh)
      #pragma unroll
      for (int cf = 0; cf < 2; ++cf) {
        int row = R + xh*16 + lc;
        int colb = cq*32 + cf*16 + 4*lg;
        float4 bv = *(const float4*)&bias1[colb];
        float s0 = acc[xh][cf][0] + bv.x;
        float s1 = acc[xh][cf][1] + bv.y;
        float s2 = acc[xh][cf][2] + bv.z;
        float s3 = acc[xh][cf][3] + bv.w;
        float u0 = s0 / (1.f + __expf(-s0));
        float u1 = s1 / (1.f + __expf(-s1));
        float u2 = s2 / (1.f + __expf(-s2));
        float u3 = s3 / (1.f + __expf(-s3));
        lds_store4bf(xb, row, colb*2, u0, u1, u2, u3);
      }
  }
  __syncthreads();

  // ---- GEMM3 (swapped): y2 = u @ w2^T + b2 -> stb via ushort4 ----
  f32x4 acc2[2][2];
  #pragma unroll
  for (int xh = 0; xh < 2; ++xh)
    #pragma unroll
    for (int cf = 0; cf < 2; ++cf) acc2[xh][cf] = (f32x4){0.f,0.f,0.f,0.f};

  #pragma unroll
  for (int ks = 0; ks < 4; ++ks) {
    bf16x8 b0 = wb_frag(wb2, cq * 2,     ks, lane);
    bf16x8 b1 = wb_frag(wb2, cq * 2 + 1, ks, lane);
    bf16x8 a0  = lds_afrag(xb, R,      ks * 32, lane);
    bf16x8 a1f = lds_afrag(xb, R + 16, ks * 32, lane);
    acc2[0][0] = __builtin_amdgcn_mfma_f32_16x16x32_bf16(b0, a0,  acc2[0][0], 0, 0, 0);
    acc2[0][1] = __builtin_amdgcn_mfma_f32_16x16x32_bf16(b1, a0,  acc2[0][1], 0, 0, 0);
    acc2[1][0] = __builtin_amdgcn_mfma_f32_16x16x32_bf16(b0, a1f, acc2[1][0], 0, 0, 0);
    acc2[1][1] = __builtin_amdgcn_mfma_f32_16x16x32_bf16(b1, a1f, acc2[1][1], 0, 0, 0);
  }

  {
    #pragma unroll
    for (int xh = 0; xh < 2; ++xh)
      #pragma unroll
      for (int cf = 0; cf < 2; ++cf) {
        int row = R + xh*16 + lc;
        int colb = cq*32 + cf*16 + 4*lg;
        float4 bv = *(const float4*)&bias2[colb];
        ushort4 o;
        o.x = f2bf(acc2[xh][cf][0] + bv.x);
        o.y = f2bf(acc2[xh][cf][1] + bv.y);
        o.z = f2bf(acc2[xh][cf][2] + bv.z);
        o.w = f2bf(acc2[xh][cf][3] + bv.w);
        *(ushort4*)(stb + row*272 + colb*2) = o;
      }
  }
  __syncthreads();

  // ---- LN2 epilogue: full-wave pattern (proven) ----
  const float ga = g2[lane], gb = g2[64 + lane];
  const float ba = b2v[lane], bbv = b2v[64 + lane];
  for (int rr = 0; rr < 8; ++rr) {
    int row = w * 8 + rr;
    float y0 = bf2f(*(const unsigned short*)(stb + row*272 + lane*2));
    float y1 = bf2f(*(const unsigned short*)(stb + row*272 + (64 + lane)*2));
    float r0 = bf2f(hnp[(pos0 + row) * 128 + lane]) + y0;
    float r1 = bf2f(hnp[(pos0 + row) * 128 + 64 + lane]) + y1;
    float s = r0 + r1, sq = r0*r0 + r1*r1;
    #pragma unroll
    for (int m = 1; m < 64; m <<= 1) { s += __shfl_xor(s, m); sq += __shfl_xor(sq, m); }
    float mu = s * (1.f/128.f);
    float var = sq * (1.f/128.f) - mu*mu;
    float rstd = rsqrtf(var + 1e-5f);
    out[(pos0 + row) * 128 + lane]      = (r0 - mu) * rstd * ga + ba;
    out[(pos0 + row) * 128 + 64 + lane] = (r1 - mu) * rstd * gb + bbv;
  }
}

extern "C" void kernel_launch(void* const* d_in, const int* in_sizes, int n_in,
                              void* d_out, int out_size, void* d_ws, size_t ws_size,
                              hipStream_t stream)
{
  const float* h    = (const float*)d_in[0];
  const void*  mask = d_in[1];
  const float* wa1  = (const float*)d_in[2];
  const float* wa2  = (const float*)d_in[3];
  const float* wv1  = (const float*)d_in[4];
  const float* wv2  = (const float*)d_in[5];
  const float* wo   = (const float*)d_in[6];
  const float* ln1s = (const float*)d_in[7];
  const float* ln1b = (const float*)d_in[8];
  const float* ln2s = (const float*)d_in[9];
  const float* ln2b = (const float*)d_in[10];
  const float* wu1  = (const float*)d_in[11];
  const float* bu1  = (const float*)d_in[12];
  const float* wu2  = (const float*)d_in[13];
  const float* bu2  = (const float*)d_in[14];

  char* ws = (char*)d_ws;
  const size_t MB = 1024*1024;
  unsigned short* vb1   = (unsigned short*)(ws + 0);        // 32 MB
  unsigned short* tbufT = (unsigned short*)(ws + 0);        // 35.7 MB (aliases vb1)
  unsigned short* vb2   = (unsigned short*)(ws + 36*MB);    // 32 MB
  unsigned short* hn    = (unsigned short*)(ws + 36*MB);    // 32 MB (aliases vb2)
  unsigned short* Bbuf  = (unsigned short*)(ws + 68*MB);    // 35.7 MB
  float* a1  = (float*)(ws + 104*MB);                       // 4 MB
  float* a2  = (float*)(ws + 108*MB);                       // 4 MB
  float* e2  = (float*)(ws + 112*MB);                       // 4 MB
  float* am1 = (float*)(ws + 116*MB);
  float* am2 = (float*)(ws + 116*MB + 16384);
  int*   flg = (int*)  (ws + 116*MB + 32768);
  int*   part= (int*)  (ws + 116*MB + 65536);               // 128 ints
  unsigned short* wb = (unsigned short*)(ws + 117*MB);      // 84 KB frag-major weights
  unsigned short* Abuf = (unsigned short*)d_out;            // 35.7 MB in 64 MB out

  k_maskpart<<<128, 256, 0, stream>>>((const unsigned int*)mask, part);
  k_maskred<<<1, 128, 0, stream>>>(part, flg);
  k_wconv<<<6, 256, 0, stream>>>(wv1, wv2, wo, wu1, wu2, wa1, wa2, wb);
  k_proj_mfma<<<2048, 512, 0, stream>>>(h, wb, a1, a2, vb1, vb2);
  k_rowmax<<<1024, 64, 0, stream>>>(a1, a2, am1, am2);
  k_e<<<512, 256, 0, stream>>>(mask, flg, a1, a2, am1, am2, e2, Abuf);
  k_prep1<<<1024, 256, 0, stream>>>(vb1, Abuf);
  k_prep2<<<dim3(32,16,2), 256, 0, stream>>>(vb2, e2, Bbuf);
  k_tri_mfma<<<dim3(2,2,272), 256, 0, stream>>>(Abuf, Bbuf, tbufT);
  k_wo_ln_mfma<<<2048, 512, 0, stream>>>(tbufT, wb, h, ln1s, ln1b, hn);
  k_ffn_ln_mfma<<<2048, 512, 0, stream>>>(hn, wb, bu1, bu2, ln2s, ln2b, (float*)d_out);
}

// Round 17
// 177.260 us; speedup vs baseline: 1.0064x; 1.0064x over previous
//
#include <hip/hip_runtime.h>

#define B_ 2
#define N_ 256
#define C_ 128
#define H_ 8

typedef __attribute__((ext_vector_type(8))) short bf16x8;
typedef __attribute__((ext_vector_type(8))) unsigned short u16x8;
typedef __attribute__((ext_vector_type(4))) float f32x4;

__device__ __forceinline__ unsigned short f2bf(float f) {
  unsigned int u = __float_as_uint(f);
  unsigned int r = (u + 0x7FFFu + ((u >> 16) & 1u)) >> 16;
  return (unsigned short)r;
}
__device__ __forceinline__ float bf2f(unsigned short u) {
  return __uint_as_float(((unsigned int)u) << 16);
}

// A-fragment from XOR-swizzled bf16 LDS tile [rows][128 cols] (256 B/row)
__device__ __forceinline__ bf16x8 lds_afrag(const char* base, int row0, int k0, int lane) {
  int row = row0 + (lane & 15);
  int cb = (k0 + 8 * (lane >> 4)) * 2;
  int byte = row * 256 + ((((cb >> 4) ^ (row & 7))) << 4);
  return *(const bf16x8*)(base + byte);
}

__device__ __forceinline__ void lds_store4bf(char* base, int row, int cbyte,
                                             float a, float b, float c, float d) {
  int byte = row * 256 + ((((cbyte >> 4) ^ (row & 7))) << 4) + (cbyte & 15);
  ushort4 o4;
  o4.x = f2bf(a); o4.y = f2bf(b); o4.z = f2bf(c); o4.w = f2bf(d);
  *(ushort4*)(base + byte) = o4;
}

// frag-major weight fetch: wbase -> [cfi][ks][lane][8] bf16
__device__ __forceinline__ bf16x8 wb_frag(const unsigned short* wbase,
                                          int cfi, int ks, int lane) {
  return *(const bf16x8*)(wbase + (((cfi * 4 + ks) * 64) + lane) * 8);
}

// ---------------- K0: mask dtype detection (parallel) ----------------
__global__ __launch_bounds__(256) void k_maskpart(const unsigned int* __restrict__ m4,
                                                  int* __restrict__ part)
{
  __shared__ int red[4];
  const int tid = threadIdx.x;
  unsigned int v = m4[blockIdx.x * 256 + tid];
  int cnt = ((v & 0xFFu) != 0) + (((v >> 8) & 0xFFu) != 0) +
            (((v >> 16) & 0xFFu) != 0) + ((v >> 24) != 0);
  #pragma unroll
  for (int m = 1; m < 64; m <<= 1) cnt += __shfl_xor(cnt, m);
  if ((tid & 63) == 0) red[tid >> 6] = cnt;
  __syncthreads();
  if (tid == 0) part[blockIdx.x] = red[0] + red[1] + red[2] + red[3];
}

__global__ __launch_bounds__(128) void k_maskred(const int* __restrict__ part,
                                                 int* __restrict__ flag)
{
  const int tid = threadIdx.x;
  int v = part[tid];
  #pragma unroll
  for (int m = 1; m < 64; m <<= 1) v += __shfl_xor(v, m);
  __shared__ int red[2];
  if ((tid & 63) == 0) red[tid >> 6] = v;
  __syncthreads();
  if (tid == 0) *flag = ((red[0] + red[1]) > 7864) ? 1 : 0;  // 1 = uint8 layout
}

// ---------------- K0b: weight conversion to fragment-major bf16 ----------------
// wb layout: [0]=wv1 [1]=wv2 [2]=wo [3]=w1 [4]=w2 (16384 each), +5*16384: wa (2048)
__global__ __launch_bounds__(256) void k_wconv(
    const float* __restrict__ wv1, const float* __restrict__ wv2,
    const float* __restrict__ wo, const float* __restrict__ w1,
    const float* __restrict__ w2,
    const float* __restrict__ wa1, const float* __restrict__ wa2,
    unsigned short* __restrict__ wb)
{
  const int m = blockIdx.x;
  const int tid = threadIdx.x;
  const int l = tid & 63;
  if (m < 5) {
    const float* W = (m == 0) ? wv1 : (m == 1) ? wv2 : (m == 2) ? wo : (m == 3) ? w1 : w2;
    unsigned short* o = wb + m * 16384;
    const int sub = tid >> 6;
    #pragma unroll
    for (int q = 0; q < 8; ++q) {
      int f = q * 4 + sub;              // fragment 0..31 (cf = f>>2, ks = f&3)
      int cf = f >> 2, ks = f & 3;
      int row = cf * 16 + (l & 15);
      int k = ks * 32 + 8 * (l >> 4);
      const float* p = W + row * 128 + k;
      float4 x = *(const float4*)p, y = *(const float4*)(p + 4);
      u16x8 t;
      t[0] = f2bf(x.x); t[1] = f2bf(x.y); t[2] = f2bf(x.z); t[3] = f2bf(x.w);
      t[4] = f2bf(y.x); t[5] = f2bf(y.y); t[6] = f2bf(y.z); t[7] = f2bf(y.w);
      *(u16x8*)(o + (f * 64 + l) * 8) = t;
    }
  } else {
    unsigned short* o = wb + 5 * 16384;
    const int ks = tid >> 6;
    int r = l & 15;
    const float* ar = (r < 8) ? (wa1 + r * 128) : (wa2 + (r - 8) * 128);
    const float* p = ar + ks * 32 + 8 * (l >> 4);
    float4 x = *(const float4*)p, y = *(const float4*)(p + 4);
    u16x8 t;
    t[0] = f2bf(x.x); t[1] = f2bf(x.y); t[2] = f2bf(x.z); t[3] = f2bf(x.w);
    t[4] = f2bf(y.x); t[5] = f2bf(y.y); t[6] = f2bf(y.z); t[7] = f2bf(y.w);
    *(u16x8*)(o + (ks * 64 + l) * 8) = t;
  }
}

// ---------------- K1: fused projections via MFMA, 64-pos tile, 8 waves ----------------
// Main GEMM swapped: mfma(wfrag, xfrag) -> thread regs = 4 consecutive channel cols
// at one position row -> ushort4 stage stores. acca (a-scores) keeps original order.
__global__ __launch_bounds__(512) void k_proj_mfma(
    const float* __restrict__ h, const unsigned short* __restrict__ wb,
    float* __restrict__ a1, float* __restrict__ a2,
    unsigned short* __restrict__ v1, unsigned short* __restrict__ v2)
{
  __shared__ __align__(16) char lds[16384 + 17408];
  char* hb  = lds;                 // bf16 swizzled h tile [64][256B]
  char* st1 = lds + 16384;         // v1 stage [32][272B]
  char* st2 = lds + 16384 + 8704;  // v2 stage [32][272B]
  const int tid = threadIdx.x, lane = tid & 63, w = tid >> 6;
  const size_t pos0 = (size_t)blockIdx.x * 64;

  const unsigned short* wbv = wb + ((w < 4) ? 0 : 16384);
  const unsigned short* wba = wb + 5 * 16384;
  const int colbase = (w & 3) * 32;
  bf16x8 bfr[2][4];
  #pragma unroll
  for (int cf = 0; cf < 2; ++cf)
    #pragma unroll
    for (int ks = 0; ks < 4; ++ks)
      bfr[cf][ks] = wb_frag(wbv, (w & 3) * 2 + cf, ks, lane);

  bf16x8 af[4];
  if (w == 0) {
    #pragma unroll
    for (int ks = 0; ks < 4; ++ks)
      af[ks] = *(const bf16x8*)(wba + (ks * 64 + lane) * 8);
  }

  {
    const float4* hg4 = (const float4*)(h + pos0 * 128);
    #pragma unroll
    for (int q = 0; q < 4; ++q) {
      int f4i = q * 512 + tid;
      float4 x = hg4[f4i];
      lds_store4bf(hb, f4i >> 5, (f4i & 31) * 8, x.x, x.y, x.z, x.w);
    }
  }
  __syncthreads();

  const int lg = lane >> 4, lc = lane & 15;
  for (int p = 0; p < 2; ++p) {
    const int R = p * 32;
    f32x4 acc[2][2];           // [xhalf][cf] (swapped: regs span channel cols)
    #pragma unroll
    for (int xh = 0; xh < 2; ++xh)
      #pragma unroll
      for (int cf = 0; cf < 2; ++cf) acc[xh][cf] = (f32x4){0.f,0.f,0.f,0.f};
    f32x4 acca[2]; acca[0] = (f32x4){0.f,0.f,0.f,0.f}; acca[1] = acca[0];

    #pragma unroll
    for (int ks = 0; ks < 4; ++ks) {
      bf16x8 a0  = lds_afrag(hb, R,      ks * 32, lane);
      bf16x8 a1f = lds_afrag(hb, R + 16, ks * 32, lane);
      #pragma unroll
      for (int cf = 0; cf < 2; ++cf) {
        acc[0][cf] = __builtin_amdgcn_mfma_f32_16x16x32_bf16(bfr[cf][ks], a0,  acc[0][cf], 0, 0, 0);
        acc[1][cf] = __builtin_amdgcn_mfma_f32_16x16x32_bf16(bfr[cf][ks], a1f, acc[1][cf], 0, 0, 0);
      }
      if (w == 0) {
        acca[0] = __builtin_amdgcn_mfma_f32_16x16x32_bf16(a0,  af[ks], acca[0], 0, 0, 0);
        acca[1] = __builtin_amdgcn_mfma_f32_16x16x32_bf16(a1f, af[ks], acca[1], 0, 0, 0);
      }
    }

    if (p) __syncthreads();
    {
      char* st = (w < 4) ? st1 : st2;
      #pragma unroll
      for (int xh = 0; xh < 2; ++xh)
        #pragma unroll
        for (int cf = 0; cf < 2; ++cf) {
          int row = xh*16 + lc;
          int colb = colbase + cf*16 + 4*lg;
          ushort4 o;
          o.x = f2bf(acc[xh][cf][0]); o.y = f2bf(acc[xh][cf][1]);
          o.z = f2bf(acc[xh][cf][2]); o.w = f2bf(acc[xh][cf][3]);
          *(ushort4*)(st + row*272 + colb*2) = o;
        }
    }
    if (w == 0) {
      #pragma unroll
      for (int rf = 0; rf < 2; ++rf)
        #pragma unroll
        for (int r = 0; r < 4; ++r) {
          size_t row = pos0 + R + rf*16 + 4*lg + r;
          float val = acca[rf][r];
          if (lc < 8) a1[row * 8 + lc] = val;
          else        a2[row * 8 + (lc - 8)] = val;
        }
    }
    __syncthreads();
    #pragma unroll
    for (int q = 0; q < 2; ++q) {
      int s = q * 512 + tid;
      int bsel = s >> 9, idx = s & 511;
      int row = idx >> 4, seg = idx & 15;
      int4 v = *(const int4*)((bsel ? st2 : st1) + row*272 + seg*16);
      unsigned short* dst = bsel ? v2 : v1;
      *(int4*)(dst + (pos0 + R + row)*128 + seg*8) = v;
    }
  }
}

// ---------------- K2: fused row maxes (rowmax1 for id<512, rowmax2 for id>=512) ----------------
__global__ __launch_bounds__(64) void k_rowmax(const float* __restrict__ a1,
                                               const float* __restrict__ a2,
                                               float* __restrict__ amax1,
                                               float* __restrict__ amax2)
{
  const int id = blockIdx.x;
  const int t = threadIdx.x;
  if (id < 512) {
    const int bi = id;
    const float* base = a1 + (size_t)bi * N_ * 8;
    float m = -1e30f;
    #pragma unroll 8
    for (int k = 0; k < 32; ++k) m = fmaxf(m, base[t + 64*k]);
    m = fmaxf(m, __shfl_xor(m, 8));
    m = fmaxf(m, __shfl_xor(m, 16));
    m = fmaxf(m, __shfl_xor(m, 32));
    if (t < 8) amax1[bi*8 + t] = m;
  } else {
    const int bj = id - 512;
    const int b = bj >> 8, j = bj & 255;
    const int hh = t & 7, igrp = t >> 3;
    float m = -1e30f;
    for (int k = 0; k < 32; ++k) {
      int i = igrp + 8*k;
      m = fmaxf(m, a2[((size_t)(b*N_ + i)*N_ + j)*8 + hh]);
    }
    m = fmaxf(m, __shfl_xor(m, 8));
    m = fmaxf(m, __shfl_xor(m, 16));
    m = fmaxf(m, __shfl_xor(m, 32));
    if (t < 8) amax2[bj*8 + t] = m;
  }
}

// ---------------- K3: exp (masked); e2 f32 natural; eb1 bf16 -> Abuf ch128+ ----------------
__global__ __launch_bounds__(256) void k_e(
    const void* __restrict__ maskraw, const int* __restrict__ modep,
    const float* __restrict__ a1, const float* __restrict__ a2,
    const float* __restrict__ am1, const float* __restrict__ am2,
    float* __restrict__ e2out, unsigned short* __restrict__ Abuf)
{
  __shared__ unsigned short eb[8 * 256];   // [h][p] bf16
  const int tid = threadIdx.x;
  const size_t pos0 = (size_t)blockIdx.x * 256;
  const size_t p = pos0 + tid;
  const int b = (int)(p >> 16), ij = (int)(p & 65535);
  const int i = ij >> 8, j = ij & 255;
  const int msk = modep[0] ? (int)((const unsigned char*)maskraw)[p]
                           : ((const int*)maskraw)[p];
  float4 x0 = *(const float4*)(a1 + p*8);
  float4 x1 = *(const float4*)(a1 + p*8 + 4);
  float4 m0 = *(const float4*)(am1 + ((size_t)(b*256 + i))*8);
  float4 m1 = *(const float4*)(am1 + ((size_t)(b*256 + i))*8 + 4);
  eb[0*256 + tid] = msk ? 0 : f2bf(__expf(x0.x - m0.x));
  eb[1*256 + tid] = msk ? 0 : f2bf(__expf(x0.y - m0.y));
  eb[2*256 + tid] = msk ? 0 : f2bf(__expf(x0.z - m0.z));
  eb[3*256 + tid] = msk ? 0 : f2bf(__expf(x0.w - m0.w));
  eb[4*256 + tid] = msk ? 0 : f2bf(__expf(x1.x - m1.x));
  eb[5*256 + tid] = msk ? 0 : f2bf(__expf(x1.y - m1.y));
  eb[6*256 + tid] = msk ? 0 : f2bf(__expf(x1.z - m1.z));
  eb[7*256 + tid] = msk ? 0 : f2bf(__expf(x1.w - m1.w));

  float4 y0 = *(const float4*)(a2 + p*8);
  float4 y1 = *(const float4*)(a2 + p*8 + 4);
  float4 n0 = *(const float4*)(am2 + ((size_t)(b*256 + j))*8);
  float4 n1 = *(const float4*)(am2 + ((size_t)(b*256 + j))*8 + 4);
  float4 o0, o1;
  o0.x = msk ? 0.f : __expf(y0.x - n0.x);
  o0.y = msk ? 0.f : __expf(y0.y - n0.y);
  o0.z = msk ? 0.f : __expf(y0.z - n0.z);
  o0.w = msk ? 0.f : __expf(y0.w - n0.w);
  o1.x = msk ? 0.f : __expf(y1.x - n1.x);
  o1.y = msk ? 0.f : __expf(y1.y - n1.y);
  o1.z = msk ? 0.f : __expf(y1.z - n1.z);
  o1.w = msk ? 0.f : __expf(y1.w - n1.w);
  *(float4*)(e2out + p*8) = o0;
  *(float4*)(e2out + p*8 + 4) = o1;

  __syncthreads();
  {
    int hh = tid >> 5, seg = tid & 31;
    int4 v = *(const int4*)((const char*)eb + hh*512 + seg*16);
    *(int4*)(Abuf + (((size_t)(b*136 + 128 + hh)) << 16) + (int)(pos0 & 65535) + seg*8) = v;
  }
}

// ---------------- K4a: pc1[c][i][l] = vb1[pos][c] * e1 (channel transpose) ----------------
__global__ __launch_bounds__(256) void k_prep1(
    const unsigned short* __restrict__ vb1, unsigned short* __restrict__ Abuf)
{
  __shared__ __align__(16) char lds[36864];  // xt [128][272B] + et [8][256B]
  char* xt = lds;
  unsigned short* et = (unsigned short*)(lds + 34816);
  const int tid = threadIdx.x;
  const size_t pos0 = (size_t)blockIdx.x * 128;
  const int b = (int)(pos0 >> 16);
  const int posl0 = (int)(pos0 & 65535);

  if (tid < 128) {
    int hh = tid >> 4, seg = tid & 15;
    int4 v = *(const int4*)(Abuf + (((size_t)(b*136 + 128 + hh)) << 16) + posl0 + seg*8);
    *(int4*)((char*)et + hh*256 + seg*16) = v;
  }
  #pragma unroll
  for (int q = 0; q < 8; ++q) {
    int s = q*256 + tid;
    int rec = s >> 4, g = s & 15;
    int4 v = *(const int4*)(vb1 + (pos0 + rec)*128 + g*8);
    *(int4*)(xt + rec*272 + g*16) = v;
  }
  __syncthreads();
  #pragma unroll
  for (int q = 0; q < 8; ++q) {
    int c = q*16 + (tid & 15);
    int pg = tid >> 4;
    int hh = c >> 4;
    u16x8 t;
    #pragma unroll
    for (int k = 0; k < 8; ++k) {
      int p = pg*8 + k;
      float xv = bf2f(*(const unsigned short*)(xt + p*272 + c*2));
      float ev = bf2f(et[hh*128 + p]);
      t[k] = f2bf(xv * ev);
    }
    *(int4*)(Abuf + (((size_t)(b*136 + c)) << 16) + posl0 + pg*8) = *(int4*)&t;
  }
}

// ---------------- K4b: pc2t[c][j][l] = vb2[(l,j)][c]*e2 ; eb2t[h][j][l] ----------------
// cw split across blockIdx.x: bx = lt*4 + cw  (grid 32 x 16 x 2)
__global__ __launch_bounds__(256) void k_prep2(
    const unsigned short* __restrict__ vb2, const float* __restrict__ e2,
    unsigned short* __restrict__ Bbuf)
{
  __shared__ __align__(16) char lds[49152];  // vt [512][80B] + et [512][16B]
  char* vt = lds;
  unsigned short* et = (unsigned short*)(lds + 40960);  // [rec][8 h] bf16
  const int tid = threadIdx.x;
  const int bx = blockIdx.x, jt = blockIdx.y, b = blockIdx.z;
  const int lt = bx >> 2, cw = bx & 3;
  const int l0 = lt*32, j0 = jt*16;

  #pragma unroll
  for (int q = 0; q < 4; ++q) {
    int s = q*256 + tid;
    int rec = s >> 1, hf = (s & 1)*4;
    int l = rec >> 4, j = rec & 15;
    size_t pos = ((size_t)b << 16) + (size_t)(l0 + l)*256 + (j0 + j);
    float4 ev = *(const float4*)(e2 + pos*8 + hf);
    ushort4 o; o.x = f2bf(ev.x); o.y = f2bf(ev.y); o.z = f2bf(ev.z); o.w = f2bf(ev.w);
    *(ushort4*)(et + rec*8 + hf) = o;
  }

  {
    #pragma unroll
    for (int q = 0; q < 8; ++q) {
      int s = q*256 + tid;
      int rec = s >> 2, g = s & 3;
      int l = rec >> 4, j = rec & 15;
      size_t pos = ((size_t)b << 16) + (size_t)(l0 + l)*256 + (j0 + j);
      int4 v = *(const int4*)(vb2 + pos*128 + cw*32 + g*8);
      *(int4*)(vt + rec*80 + g*16) = v;
    }
    __syncthreads();
    #pragma unroll
    for (int q = 0; q < 8; ++q) {
      int loff = tid & 3, j = (tid >> 2) & 15, cs = tid >> 6;
      int cl = q*4 + cs;
      int c = cw*32 + cl;
      int hh = c >> 4;
      u16x8 t;
      #pragma unroll
      for (int k = 0; k < 8; ++k) {
        int l = loff*8 + k;
        int rec = l*16 + j;
        float xv = bf2f(*(const unsigned short*)(vt + rec*80 + cl*2));
        float ev = bf2f(et[rec*8 + hh]);
        t[k] = f2bf(xv * ev);
      }
      *(int4*)(Bbuf + (((size_t)(b*136 + c)) << 16) + (size_t)(j0 + j)*256 + l0 + loff*8) = *(int4*)&t;
    }
  }
  if (cw == 0) {
    #pragma unroll
    for (int q = 0; q < 2; ++q) {
      int s = q*256 + tid;
      int loff = s & 3, j = (s >> 2) & 15, hh = s >> 6;
      u16x8 t;
      #pragma unroll
      for (int k = 0; k < 8; ++k) {
        int l = loff*8 + k;
        int rec = l*16 + j;
        t[k] = et[rec*8 + hh];
      }
      *(int4*)(Bbuf + (((size_t)(b*136 + 128 + hh)) << 16) + (size_t)(j0 + j)*256 + l0 + loff*8) = *(int4*)&t;
    }
  }
}

// ---------------- K5: batched 256^3 GEMM over 272 channels (tri + denom) ----------------
// XCD-aware block swizzle (proven r15) + swapped-operand MFMA (ushort4 C-stage).
__global__ __launch_bounds__(256) void k_tri_mfma(
    const unsigned short* __restrict__ Ab, const unsigned short* __restrict__ Bb,
    unsigned short* __restrict__ outT)
{
  __shared__ __align__(16) char lds[34816];
  char* lA = lds;
  char* lB = lds + 10240;
  const int tid = threadIdx.x, lane = tid & 63, w = tid >> 6;
  const int bid = blockIdx.x + 2 * blockIdx.y + 4 * blockIdx.z;  // 0..1087
  const int xcd = bid & 7;
  const int slot = bid >> 3;                 // 0..135
  const int ch_all = xcd * 34 + (slot >> 2); // 0..271
  const int tile = slot & 3;
  const int jt = tile & 1, it = tile >> 1;
  const int b = ch_all / 136, ch = ch_all - b*136;
  const size_t mbase = ((size_t)(b*136 + ch)) << 16;
  const int i0 = it*128, j0 = jt*128;
  const int r4 = tid >> 2, g4 = tid & 3;

  const unsigned short* gA0 = Ab + mbase + (size_t)(i0 + r4)*256 + g4*8;
  const unsigned short* gA1 = gA0 + 64*256;
  const unsigned short* gB0 = Bb + mbase + (size_t)(j0 + r4)*256 + g4*8;
  const unsigned short* gB1 = gB0 + 64*256;
  char* sA0 = lA + r4*80 + g4*16;
  char* sA1 = sA0 + 64*80;
  char* sB0 = lB + r4*80 + g4*16;
  char* sB1 = sB0 + 64*80;

  const int wr = w >> 1, wc = w & 1;
  const char* fA = lA + (wr*64 + (lane & 15))*80 + (lane >> 4)*16;
  const char* fB = lB + (wc*64 + (lane & 15))*80 + (lane >> 4)*16;
  const int lg = lane >> 4, lc = lane & 15;

  f32x4 acc[4][4];
  #pragma unroll
  for (int rf = 0; rf < 4; ++rf)
    #pragma unroll
    for (int cf = 0; cf < 4; ++cf) acc[rf][cf] = (f32x4){0.f,0.f,0.f,0.f};

  int4 ra0 = *(const int4*)gA0;
  int4 ra1 = *(const int4*)gA1;
  int4 rb0 = *(const int4*)gB0;
  int4 rb1 = *(const int4*)gB1;

  for (int ks = 0; ks < 8; ++ks) {
    __syncthreads();
    *(int4*)sA0 = ra0; *(int4*)sA1 = ra1;
    *(int4*)sB0 = rb0; *(int4*)sB1 = rb1;
    __syncthreads();
    if (ks < 7) {
      const int off = (ks + 1)*32;
      ra0 = *(const int4*)(gA0 + off);
      ra1 = *(const int4*)(gA1 + off);
      rb0 = *(const int4*)(gB0 + off);
      rb1 = *(const int4*)(gB1 + off);
    }
    bf16x8 af[4], bfv[4];
    #pragma unroll
    for (int rf = 0; rf < 4; ++rf) af[rf] = *(const bf16x8*)(fA + rf*16*80);
    #pragma unroll
    for (int cf = 0; cf < 4; ++cf) bfv[cf] = *(const bf16x8*)(fB + cf*16*80);
    // swapped: D "row regs" follow bfv (j), "col lane" follows af (i)
    #pragma unroll
    for (int rf = 0; rf < 4; ++rf)
      #pragma unroll
      for (int cf = 0; cf < 4; ++cf)
        acc[rf][cf] = __builtin_amdgcn_mfma_f32_16x16x32_bf16(bfv[cf], af[rf], acc[rf][cf], 0, 0, 0);
  }

  __syncthreads();
  #pragma unroll
  for (int rf = 0; rf < 4; ++rf)
    #pragma unroll
    for (int cf = 0; cf < 4; ++cf) {
      int il = wr*64 + rf*16 + lc;
      int jl = wc*64 + cf*16 + 4*lg;
      ushort4 o;
      o.x = f2bf(acc[rf][cf][0]); o.y = f2bf(acc[rf][cf][1]);
      o.z = f2bf(acc[rf][cf][2]); o.w = f2bf(acc[rf][cf][3]);
      *(ushort4*)(lds + il*272 + jl*2) = o;
    }
  __syncthreads();
  #pragma unroll
  for (int q = 0; q < 8; ++q) {
    int row = q*16 + (tid >> 4), seg = tid & 15;
    int4 v = *(const int4*)(lds + row*272 + seg*16);
    *(int4*)(outT + mbase + (size_t)(i0 + row)*256 + j0 + seg*8) = v;
  }
}

// ---------------- K6: x = t/denom ; y = x@wo^T ; hn = bf16(LN1(h + y))
//                  Swapped-operand MFMA (proven r16) + full-wave LN epilogue ----------------
__global__ __launch_bounds__(512) void k_wo_ln_mfma(
    const unsigned short* __restrict__ tT, const unsigned short* __restrict__ wb,
    const float* __restrict__ h,
    const float* __restrict__ g1, const float* __restrict__ bb1,
    unsigned short* __restrict__ hn)
{
  __shared__ __align__(16) char xb[64 * 256];
  __shared__ __align__(16) char stb[64 * 272];   // bf16 stage [64][136]
  const int tid = threadIdx.x, lane = tid & 63, w = tid >> 6;
  const size_t pos0 = (size_t)blockIdx.x * 64;
  const int b = (int)(pos0 >> 16);
  const int posl0 = (int)(pos0 & 65535);
  const int rh = w >> 2, cq = w & 3;
  const int R = rh * 32;
  const int lg = lane >> 4, lc = lane & 15;

  // ---- stage-in: x = t/denom -> xb ----
  #pragma unroll
  for (int it2 = 0; it2 < 2; ++it2) {
    int c = it2*64 + (tid >> 3);
    int poff = (tid & 7)*8;
    u16x8 tv = *(const u16x8*)(tT + (((size_t)(b*136 + c)) << 16) + posl0 + poff);
    u16x8 dv = *(const u16x8*)(tT + (((size_t)(b*136 + 128 + (c >> 4))) << 16) + posl0 + poff);
    int cb = c*2;
    #pragma unroll
    for (int k = 0; k < 8; ++k) {
      float x = bf2f(tv[k]) / (bf2f(dv[k]) + 1e-6f);
      int p = poff + k;
      int byte = p*256 + ((((cb >> 4) ^ (p & 7))) << 4) + (cb & 15);
      *(unsigned short*)(xb + byte) = f2bf(x);
    }
  }
  __syncthreads();

  // ---- GEMM (swapped): y = x @ wo^T -> stb via ushort4 ----
  {
    const unsigned short* wbo = wb + 2 * 16384;
    f32x4 acc[2][2];          // [xhalf][cf]
    #pragma unroll
    for (int xh = 0; xh < 2; ++xh)
      #pragma unroll
      for (int cf = 0; cf < 2; ++cf) acc[xh][cf] = (f32x4){0.f,0.f,0.f,0.f};
    #pragma unroll
    for (int ks = 0; ks < 4; ++ks) {
      bf16x8 a0  = lds_afrag(xb, R,      ks * 32, lane);
      bf16x8 a1f = lds_afrag(xb, R + 16, ks * 32, lane);
      #pragma unroll
      for (int cf = 0; cf < 2; ++cf) {
        bf16x8 bf = wb_frag(wbo, cq * 2 + cf, ks, lane);
        acc[0][cf] = __builtin_amdgcn_mfma_f32_16x16x32_bf16(bf, a0,  acc[0][cf], 0, 0, 0);
        acc[1][cf] = __builtin_amdgcn_mfma_f32_16x16x32_bf16(bf, a1f, acc[1][cf], 0, 0, 0);
      }
    }
    #pragma unroll
    for (int xh = 0; xh < 2; ++xh)
      #pragma unroll
      for (int cf = 0; cf < 2; ++cf) {
        int row = R + xh*16 + lc;
        int colb = cq*32 + cf*16 + 4*lg;
        ushort4 o;
        o.x = f2bf(acc[xh][cf][0]); o.y = f2bf(acc[xh][cf][1]);
        o.z = f2bf(acc[xh][cf][2]); o.w = f2bf(acc[xh][cf][3]);
        *(ushort4*)(stb + row*272 + colb*2) = o;
      }
  }
  __syncthreads();

  // ---- LN1 epilogue: full-wave pattern (proven r6/r11/r13/r14/r15/r16) ----
  const float ga = g1[lane], gb = g1[64 + lane];
  const float ba = bb1[lane], bbv = bb1[64 + lane];
  for (int rr = 0; rr < 8; ++rr) {
    int row = w * 8 + rr;
    float y0 = bf2f(*(const unsigned short*)(stb + row*272 + lane*2));
    float y1 = bf2f(*(const unsigned short*)(stb + row*272 + (64 + lane)*2));
    float r0 = h[(pos0 + row) * 128 + lane] + y0;
    float r1 = h[(pos0 + row) * 128 + 64 + lane] + y1;
    float s = r0 + r1, sq = r0*r0 + r1*r1;
    #pragma unroll
    for (int m = 1; m < 64; m <<= 1) { s += __shfl_xor(s, m); sq += __shfl_xor(sq, m); }
    float mu = s * (1.f/128.f);
    float var = sq * (1.f/128.f) - mu*mu;
    float rstd = rsqrtf(var + 1e-5f);
    hn[(pos0 + row) * 128 + lane]      = f2bf((r0 - mu) * rstd * ga + ba);
    hn[(pos0 + row) * 128 + 64 + lane] = f2bf((r1 - mu) * rstd * gb + bbv);
  }
}

// ---------------- K7: FFN(silu) + residual + LN2 -> out (swapped MFMA, vector stores) ----------------
__global__ __launch_bounds__(512) void k_ffn_ln_mfma(
    const unsigned short* __restrict__ hnp, const unsigned short* __restrict__ wb,
    const float* __restrict__ bias1, const float* __restrict__ bias2,
    const float* __restrict__ g2, const float* __restrict__ b2v,
    float* __restrict__ out)
{
  __shared__ __align__(16) char xb[64 * 256];       // x then u (bf16 swizzled)
  __shared__ __align__(16) char stb[64 * 272];      // bf16 stage [64][136]
  const int tid = threadIdx.x, lane = tid & 63, w = tid >> 6;
  const size_t pos0 = (size_t)blockIdx.x * 64;
  const int rh = w >> 2, cq = w & 3;
  const int R = rh * 32;
  const int lg = lane >> 4, lc = lane & 15;
  const unsigned short* wb1 = wb + 3 * 16384;
  const unsigned short* wb2 = wb + 4 * 16384;

  bf16x8 bf1[2][4];
  #pragma unroll
  for (int cf = 0; cf < 2; ++cf)
    #pragma unroll
    for (int ks = 0; ks < 4; ++ks)
      bf1[cf][ks] = wb_frag(wb1, cq * 2 + cf, ks, lane);

  #pragma unroll
  for (int q = 0; q < 2; ++q) {
    int s = q*512 + tid;
    int row = s >> 4, g = s & 15;
    int4 v = *(const int4*)(hnp + (pos0 + row)*128 + g*8);
    *(int4*)(xb + row*256 + (((g ^ (row & 7))) << 4)) = v;
  }
  __syncthreads();

  // ---- GEMM1 (swapped): acc[xh][cf], u = silu(acc + b1) -> xb via lds_store4bf ----
  f32x4 acc[2][2];
  #pragma unroll
  for (int xh = 0; xh < 2; ++xh)
    #pragma unroll
    for (int cf = 0; cf < 2; ++cf) acc[xh][cf] = (f32x4){0.f,0.f,0.f,0.f};

  #pragma unroll
  for (int ks = 0; ks < 4; ++ks) {
    bf16x8 a0  = lds_afrag(xb, R,      ks * 32, lane);
    bf16x8 a1f = lds_afrag(xb, R + 16, ks * 32, lane);
    #pragma unroll
    for (int cf = 0; cf < 2; ++cf) {
      acc[0][cf] = __builtin_amdgcn_mfma_f32_16x16x32_bf16(bf1[cf][ks], a0,  acc[0][cf], 0, 0, 0);
      acc[1][cf] = __builtin_amdgcn_mfma_f32_16x16x32_bf16(bf1[cf][ks], a1f, acc[1][cf], 0, 0, 0);
    }
  }
  __syncthreads();

  {
    #pragma unroll
    for (int xh = 0; xh < 2; ++xh)
      #pragma unroll
      for (int cf = 0; cf < 2; ++cf) {
        int row = R + xh*16 + lc;
        int colb = cq*32 + cf*16 + 4*lg;
        float4 bv = *(const float4*)&bias1[colb];
        float s0 = acc[xh][cf][0] + bv.x;
        float s1 = acc[xh][cf][1] + bv.y;
        float s2 = acc[xh][cf][2] + bv.z;
        float s3 = acc[xh][cf][3] + bv.w;
        float u0 = s0 / (1.f + __expf(-s0));
        float u1 = s1 / (1.f + __expf(-s1));
        float u2 = s2 / (1.f + __expf(-s2));
        float u3 = s3 / (1.f + __expf(-s3));
        lds_store4bf(xb, row, colb*2, u0, u1, u2, u3);
      }
  }
  __syncthreads();

  // ---- GEMM3 (swapped): y2 = u @ w2^T + b2 -> stb via ushort4 ----
  f32x4 acc2[2][2];
  #pragma unroll
  for (int xh = 0; xh < 2; ++xh)
    #pragma unroll
    for (int cf = 0; cf < 2; ++cf) acc2[xh][cf] = (f32x4){0.f,0.f,0.f,0.f};

  #pragma unroll
  for (int ks = 0; ks < 4; ++ks) {
    bf16x8 b0 = wb_frag(wb2, cq * 2,     ks, lane);
    bf16x8 b1 = wb_frag(wb2, cq * 2 + 1, ks, lane);
    bf16x8 a0  = lds_afrag(xb, R,      ks * 32, lane);
    bf16x8 a1f = lds_afrag(xb, R + 16, ks * 32, lane);
    acc2[0][0] = __builtin_amdgcn_mfma_f32_16x16x32_bf16(b0, a0,  acc2[0][0], 0, 0, 0);
    acc2[0][1] = __builtin_amdgcn_mfma_f32_16x16x32_bf16(b1, a0,  acc2[0][1], 0, 0, 0);
    acc2[1][0] = __builtin_amdgcn_mfma_f32_16x16x32_bf16(b0, a1f, acc2[1][0], 0, 0, 0);
    acc2[1][1] = __builtin_amdgcn_mfma_f32_16x16x32_bf16(b1, a1f, acc2[1][1], 0, 0, 0);
  }

  {
    #pragma unroll
    for (int xh = 0; xh < 2; ++xh)
      #pragma unroll
      for (int cf = 0; cf < 2; ++cf) {
        int row = R + xh*16 + lc;
        int colb = cq*32 + cf*16 + 4*lg;
        float4 bv = *(const float4*)&bias2[colb];
        ushort4 o;
        o.x = f2bf(acc2[xh][cf][0] + bv.x);
        o.y = f2bf(acc2[xh][cf][1] + bv.y);
        o.z = f2bf(acc2[xh][cf][2] + bv.z);
        o.w = f2bf(acc2[xh][cf][3] + bv.w);
        *(ushort4*)(stb + row*272 + colb*2) = o;
      }
  }
  __syncthreads();

  // ---- LN2 epilogue: full-wave pattern (proven) ----
  const float ga = g2[lane], gb = g2[64 + lane];
  const float ba = b2v[lane], bbv = b2v[64 + lane];
  for (int rr = 0; rr < 8; ++rr) {
    int row = w * 8 + rr;
    float y0 = bf2f(*(const unsigned short*)(stb + row*272 + lane*2));
    float y1 = bf2f(*(const unsigned short*)(stb + row*272 + (64 + lane)*2));
    float r0 = bf2f(hnp[(pos0 + row) * 128 + lane]) + y0;
    float r1 = bf2f(hnp[(pos0 + row) * 128 + 64 + lane]) + y1;
    float s = r0 + r1, sq = r0*r0 + r1*r1;
    #pragma unroll
    for (int m = 1; m < 64; m <<= 1) { s += __shfl_xor(s, m); sq += __shfl_xor(sq, m); }
    float mu = s * (1.f/128.f);
    float var = sq * (1.f/128.f) - mu*mu;
    float rstd = rsqrtf(var + 1e-5f);
    out[(pos0 + row) * 128 + lane]      = (r0 - mu) * rstd * ga + ba;
    out[(pos0 + row) * 128 + 64 + lane] = (r1 - mu) * rstd * gb + bbv;
  }
}

extern "C" void kernel_launch(void* const* d_in, const int* in_sizes, int n_in,
                              void* d_out, int out_size, void* d_ws, size_t ws_size,
                              hipStream_t stream)
{
  const float* h    = (const float*)d_in[0];
  const void*  mask = d_in[1];
  const float* wa1  = (const float*)d_in[2];
  const float* wa2  = (const float*)d_in[3];
  const float* wv1  = (const float*)d_in[4];
  const float* wv2  = (const float*)d_in[5];
  const float* wo   = (const float*)d_in[6];
  const float* ln1s = (const float*)d_in[7];
  const float* ln1b = (const float*)d_in[8];
  const float* ln2s = (const float*)d_in[9];
  const float* ln2b = (const float*)d_in[10];
  const float* wu1  = (const float*)d_in[11];
  const float* bu1  = (const float*)d_in[12];
  const float* wu2  = (const float*)d_in[13];
  const float* bu2  = (const float*)d_in[14];

  char* ws = (char*)d_ws;
  const size_t MB = 1024*1024;
  unsigned short* vb1   = (unsigned short*)(ws + 0);        // 32 MB
  unsigned short* tbufT = (unsigned short*)(ws + 0);        // 35.7 MB (aliases vb1)
  unsigned short* vb2   = (unsigned short*)(ws + 36*MB);    // 32 MB
  unsigned short* hn    = (unsigned short*)(ws + 36*MB);    // 32 MB (aliases vb2)
  unsigned short* Bbuf  = (unsigned short*)(ws + 68*MB);    // 35.7 MB
  float* a1  = (float*)(ws + 104*MB);                       // 4 MB
  float* a2  = (float*)(ws + 108*MB);                       // 4 MB
  float* e2  = (float*)(ws + 112*MB);                       // 4 MB
  float* am1 = (float*)(ws + 116*MB);
  float* am2 = (float*)(ws + 116*MB + 16384);
  int*   flg = (int*)  (ws + 116*MB + 32768);
  int*   part= (int*)  (ws + 116*MB + 65536);               // 128 ints
  unsigned short* wb = (unsigned short*)(ws + 117*MB);      // 84 KB frag-major weights
  unsigned short* Abuf = (unsigned short*)d_out;            // 35.7 MB in 64 MB out

  k_maskpart<<<128, 256, 0, stream>>>((const unsigned int*)mask, part);
  k_maskred<<<1, 128, 0, stream>>>(part, flg);
  k_wconv<<<6, 256, 0, stream>>>(wv1, wv2, wo, wu1, wu2, wa1, wa2, wb);
  k_proj_mfma<<<2048, 512, 0, stream>>>(h, wb, a1, a2, vb1, vb2);
  k_rowmax<<<1024, 64, 0, stream>>>(a1, a2, am1, am2);
  k_e<<<512, 256, 0, stream>>>(mask, flg, a1, a2, am1, am2, e2, Abuf);
  k_prep1<<<1024, 256, 0, stream>>>(vb1, Abuf);
  k_prep2<<<dim3(32,16,2), 256, 0, stream>>>(vb2, e2, Bbuf);
  k_tri_mfma<<<dim3(2,2,272), 256, 0, stream>>>(Abuf, Bbuf, tbufT);
  k_wo_ln_mfma<<<2048, 512, 0, stream>>>(tbufT, wb, h, ln1s, ln1b, hn);
  k_ffn_ln_mfma<<<2048, 512, 0, stream>>>(hn, wb, bu1, bu2, ln2s, ln2b, (float*)d_out);
}

// Round 18
// 175.162 us; speedup vs baseline: 1.0185x; 1.0120x over previous
//
#include <hip/hip_runtime.h>

#define B_ 2
#define N_ 256
#define C_ 128
#define H_ 8

typedef __attribute__((ext_vector_type(8))) short bf16x8;
typedef __attribute__((ext_vector_type(8))) unsigned short u16x8;
typedef __attribute__((ext_vector_type(4))) float f32x4;

__device__ __forceinline__ unsigned short f2bf(float f) {
  unsigned int u = __float_as_uint(f);
  unsigned int r = (u + 0x7FFFu + ((u >> 16) & 1u)) >> 16;
  return (unsigned short)r;
}
__device__ __forceinline__ float bf2f(unsigned short u) {
  return __uint_as_float(((unsigned int)u) << 16);
}

// A-fragment from XOR-swizzled bf16 LDS tile [rows][128 cols] (256 B/row)
__device__ __forceinline__ bf16x8 lds_afrag(const char* base, int row0, int k0, int lane) {
  int row = row0 + (lane & 15);
  int cb = (k0 + 8 * (lane >> 4)) * 2;
  int byte = row * 256 + ((((cb >> 4) ^ (row & 7))) << 4);
  return *(const bf16x8*)(base + byte);
}

__device__ __forceinline__ void lds_store4bf(char* base, int row, int cbyte,
                                             float a, float b, float c, float d) {
  int byte = row * 256 + ((((cbyte >> 4) ^ (row & 7))) << 4) + (cbyte & 15);
  ushort4 o4;
  o4.x = f2bf(a); o4.y = f2bf(b); o4.z = f2bf(c); o4.w = f2bf(d);
  *(ushort4*)(base + byte) = o4;
}

// frag-major weight fetch: wbase -> [cfi][ks][lane][8] bf16
__device__ __forceinline__ bf16x8 wb_frag(const unsigned short* wbase,
                                          int cfi, int ks, int lane) {
  return *(const bf16x8*)(wbase + (((cfi * 4 + ks) * 64) + lane) * 8);
}

// ---------------- K0: mask dtype detection (parallel) ----------------
__global__ __launch_bounds__(256) void k_maskpart(const unsigned int* __restrict__ m4,
                                                  int* __restrict__ part)
{
  __shared__ int red[4];
  const int tid = threadIdx.x;
  unsigned int v = m4[blockIdx.x * 256 + tid];
  int cnt = ((v & 0xFFu) != 0) + (((v >> 8) & 0xFFu) != 0) +
            (((v >> 16) & 0xFFu) != 0) + ((v >> 24) != 0);
  #pragma unroll
  for (int m = 1; m < 64; m <<= 1) cnt += __shfl_xor(cnt, m);
  if ((tid & 63) == 0) red[tid >> 6] = cnt;
  __syncthreads();
  if (tid == 0) part[blockIdx.x] = red[0] + red[1] + red[2] + red[3];
}

__global__ __launch_bounds__(128) void k_maskred(const int* __restrict__ part,
                                                 int* __restrict__ flag)
{
  const int tid = threadIdx.x;
  int v = part[tid];
  #pragma unroll
  for (int m = 1; m < 64; m <<= 1) v += __shfl_xor(v, m);
  __shared__ int red[2];
  if ((tid & 63) == 0) red[tid >> 6] = v;
  __syncthreads();
  if (tid == 0) *flag = ((red[0] + red[1]) > 7864) ? 1 : 0;  // 1 = uint8 layout
}

// ---------------- K0b: weight conversion to fragment-major bf16 ----------------
// wb layout: [0]=wv1 [1]=wv2 [2]=wo [3]=w1 [4]=w2 (16384 each), +5*16384: wa (2048)
__global__ __launch_bounds__(256) void k_wconv(
    const float* __restrict__ wv1, const float* __restrict__ wv2,
    const float* __restrict__ wo, const float* __restrict__ w1,
    const float* __restrict__ w2,
    const float* __restrict__ wa1, const float* __restrict__ wa2,
    unsigned short* __restrict__ wb)
{
  const int m = blockIdx.x;
  const int tid = threadIdx.x;
  const int l = tid & 63;
  if (m < 5) {
    const float* W = (m == 0) ? wv1 : (m == 1) ? wv2 : (m == 2) ? wo : (m == 3) ? w1 : w2;
    unsigned short* o = wb + m * 16384;
    const int sub = tid >> 6;
    #pragma unroll
    for (int q = 0; q < 8; ++q) {
      int f = q * 4 + sub;              // fragment 0..31 (cf = f>>2, ks = f&3)
      int cf = f >> 2, ks = f & 3;
      int row = cf * 16 + (l & 15);
      int k = ks * 32 + 8 * (l >> 4);
      const float* p = W + row * 128 + k;
      float4 x = *(const float4*)p, y = *(const float4*)(p + 4);
      u16x8 t;
      t[0] = f2bf(x.x); t[1] = f2bf(x.y); t[2] = f2bf(x.z); t[3] = f2bf(x.w);
      t[4] = f2bf(y.x); t[5] = f2bf(y.y); t[6] = f2bf(y.z); t[7] = f2bf(y.w);
      *(u16x8*)(o + (f * 64 + l) * 8) = t;
    }
  } else {
    unsigned short* o = wb + 5 * 16384;
    const int ks = tid >> 6;
    int r = l & 15;
    const float* ar = (r < 8) ? (wa1 + r * 128) : (wa2 + (r - 8) * 128);
    const float* p = ar + ks * 32 + 8 * (l >> 4);
    float4 x = *(const float4*)p, y = *(const float4*)(p + 4);
    u16x8 t;
    t[0] = f2bf(x.x); t[1] = f2bf(x.y); t[2] = f2bf(x.z); t[3] = f2bf(x.w);
    t[4] = f2bf(y.x); t[5] = f2bf(y.y); t[6] = f2bf(y.z); t[7] = f2bf(y.w);
    *(u16x8*)(o + (ks * 64 + l) * 8) = t;
  }
}

// ---------------- K1: fused projections via MFMA, 64-pos tile, 8 waves ----------------
// Main GEMM swapped: mfma(wfrag, xfrag) -> thread regs = 4 consecutive channel cols
// at one position row -> ushort4 stage stores. acca (a-scores) keeps original order.
__global__ __launch_bounds__(512) void k_proj_mfma(
    const float* __restrict__ h, const unsigned short* __restrict__ wb,
    float* __restrict__ a1, float* __restrict__ a2,
    unsigned short* __restrict__ v1, unsigned short* __restrict__ v2)
{
  __shared__ __align__(16) char lds[16384 + 17408];
  char* hb  = lds;                 // bf16 swizzled h tile [64][256B]
  char* st1 = lds + 16384;         // v1 stage [32][272B]
  char* st2 = lds + 16384 + 8704;  // v2 stage [32][272B]
  const int tid = threadIdx.x, lane = tid & 63, w = tid >> 6;
  const size_t pos0 = (size_t)blockIdx.x * 64;

  const unsigned short* wbv = wb + ((w < 4) ? 0 : 16384);
  const unsigned short* wba = wb + 5 * 16384;
  const int colbase = (w & 3) * 32;
  bf16x8 bfr[2][4];
  #pragma unroll
  for (int cf = 0; cf < 2; ++cf)
    #pragma unroll
    for (int ks = 0; ks < 4; ++ks)
      bfr[cf][ks] = wb_frag(wbv, (w & 3) * 2 + cf, ks, lane);

  bf16x8 af[4];
  if (w == 0) {
    #pragma unroll
    for (int ks = 0; ks < 4; ++ks)
      af[ks] = *(const bf16x8*)(wba + (ks * 64 + lane) * 8);
  }

  {
    const float4* hg4 = (const float4*)(h + pos0 * 128);
    #pragma unroll
    for (int q = 0; q < 4; ++q) {
      int f4i = q * 512 + tid;
      float4 x = hg4[f4i];
      lds_store4bf(hb, f4i >> 5, (f4i & 31) * 8, x.x, x.y, x.z, x.w);
    }
  }
  __syncthreads();

  const int lg = lane >> 4, lc = lane & 15;
  for (int p = 0; p < 2; ++p) {
    const int R = p * 32;
    f32x4 acc[2][2];           // [xhalf][cf] (swapped: regs span channel cols)
    #pragma unroll
    for (int xh = 0; xh < 2; ++xh)
      #pragma unroll
      for (int cf = 0; cf < 2; ++cf) acc[xh][cf] = (f32x4){0.f,0.f,0.f,0.f};
    f32x4 acca[2]; acca[0] = (f32x4){0.f,0.f,0.f,0.f}; acca[1] = acca[0];

    #pragma unroll
    for (int ks = 0; ks < 4; ++ks) {
      bf16x8 a0  = lds_afrag(hb, R,      ks * 32, lane);
      bf16x8 a1f = lds_afrag(hb, R + 16, ks * 32, lane);
      #pragma unroll
      for (int cf = 0; cf < 2; ++cf) {
        acc[0][cf] = __builtin_amdgcn_mfma_f32_16x16x32_bf16(bfr[cf][ks], a0,  acc[0][cf], 0, 0, 0);
        acc[1][cf] = __builtin_amdgcn_mfma_f32_16x16x32_bf16(bfr[cf][ks], a1f, acc[1][cf], 0, 0, 0);
      }
      if (w == 0) {
        acca[0] = __builtin_amdgcn_mfma_f32_16x16x32_bf16(a0,  af[ks], acca[0], 0, 0, 0);
        acca[1] = __builtin_amdgcn_mfma_f32_16x16x32_bf16(a1f, af[ks], acca[1], 0, 0, 0);
      }
    }

    if (p) __syncthreads();
    {
      char* st = (w < 4) ? st1 : st2;
      #pragma unroll
      for (int xh = 0; xh < 2; ++xh)
        #pragma unroll
        for (int cf = 0; cf < 2; ++cf) {
          int row = xh*16 + lc;
          int colb = colbase + cf*16 + 4*lg;
          ushort4 o;
          o.x = f2bf(acc[xh][cf][0]); o.y = f2bf(acc[xh][cf][1]);
          o.z = f2bf(acc[xh][cf][2]); o.w = f2bf(acc[xh][cf][3]);
          *(ushort4*)(st + row*272 + colb*2) = o;
        }
    }
    if (w == 0) {
      #pragma unroll
      for (int rf = 0; rf < 2; ++rf)
        #pragma unroll
        for (int r = 0; r < 4; ++r) {
          size_t row = pos0 + R + rf*16 + 4*lg + r;
          float val = acca[rf][r];
          if (lc < 8) a1[row * 8 + lc] = val;
          else        a2[row * 8 + (lc - 8)] = val;
        }
    }
    __syncthreads();
    #pragma unroll
    for (int q = 0; q < 2; ++q) {
      int s = q * 512 + tid;
      int bsel = s >> 9, idx = s & 511;
      int row = idx >> 4, seg = idx & 15;
      int4 v = *(const int4*)((bsel ? st2 : st1) + row*272 + seg*16);
      unsigned short* dst = bsel ? v2 : v1;
      *(int4*)(dst + (pos0 + R + row)*128 + seg*8) = v;
    }
  }
}

// ---------------- K2: fused row maxes (rowmax1 for id<512, rowmax2 for id>=512) ----------------
__global__ __launch_bounds__(64) void k_rowmax(const float* __restrict__ a1,
                                               const float* __restrict__ a2,
                                               float* __restrict__ amax1,
                                               float* __restrict__ amax2)
{
  const int id = blockIdx.x;
  const int t = threadIdx.x;
  if (id < 512) {
    const int bi = id;
    const float* base = a1 + (size_t)bi * N_ * 8;
    float m = -1e30f;
    #pragma unroll 8
    for (int k = 0; k < 32; ++k) m = fmaxf(m, base[t + 64*k]);
    m = fmaxf(m, __shfl_xor(m, 8));
    m = fmaxf(m, __shfl_xor(m, 16));
    m = fmaxf(m, __shfl_xor(m, 32));
    if (t < 8) amax1[bi*8 + t] = m;
  } else {
    const int bj = id - 512;
    const int b = bj >> 8, j = bj & 255;
    const int hh = t & 7, igrp = t >> 3;
    float m = -1e30f;
    for (int k = 0; k < 32; ++k) {
      int i = igrp + 8*k;
      m = fmaxf(m, a2[((size_t)(b*N_ + i)*N_ + j)*8 + hh]);
    }
    m = fmaxf(m, __shfl_xor(m, 8));
    m = fmaxf(m, __shfl_xor(m, 16));
    m = fmaxf(m, __shfl_xor(m, 32));
    if (t < 8) amax2[bj*8 + t] = m;
  }
}

// ---------------- K3: exp (masked); e2 f32 natural; eb1 bf16 -> Abuf ch128+ ----------------
__global__ __launch_bounds__(256) void k_e(
    const void* __restrict__ maskraw, const int* __restrict__ modep,
    const float* __restrict__ a1, const float* __restrict__ a2,
    const float* __restrict__ am1, const float* __restrict__ am2,
    float* __restrict__ e2out, unsigned short* __restrict__ Abuf)
{
  __shared__ unsigned short eb[8 * 256];   // [h][p] bf16
  const int tid = threadIdx.x;
  const size_t pos0 = (size_t)blockIdx.x * 256;
  const size_t p = pos0 + tid;
  const int b = (int)(p >> 16), ij = (int)(p & 65535);
  const int i = ij >> 8, j = ij & 255;
  const int msk = modep[0] ? (int)((const unsigned char*)maskraw)[p]
                           : ((const int*)maskraw)[p];
  float4 x0 = *(const float4*)(a1 + p*8);
  float4 x1 = *(const float4*)(a1 + p*8 + 4);
  float4 m0 = *(const float4*)(am1 + ((size_t)(b*256 + i))*8);
  float4 m1 = *(const float4*)(am1 + ((size_t)(b*256 + i))*8 + 4);
  eb[0*256 + tid] = msk ? 0 : f2bf(__expf(x0.x - m0.x));
  eb[1*256 + tid] = msk ? 0 : f2bf(__expf(x0.y - m0.y));
  eb[2*256 + tid] = msk ? 0 : f2bf(__expf(x0.z - m0.z));
  eb[3*256 + tid] = msk ? 0 : f2bf(__expf(x0.w - m0.w));
  eb[4*256 + tid] = msk ? 0 : f2bf(__expf(x1.x - m1.x));
  eb[5*256 + tid] = msk ? 0 : f2bf(__expf(x1.y - m1.y));
  eb[6*256 + tid] = msk ? 0 : f2bf(__expf(x1.z - m1.z));
  eb[7*256 + tid] = msk ? 0 : f2bf(__expf(x1.w - m1.w));

  float4 y0 = *(const float4*)(a2 + p*8);
  float4 y1 = *(const float4*)(a2 + p*8 + 4);
  float4 n0 = *(const float4*)(am2 + ((size_t)(b*256 + j))*8);
  float4 n1 = *(const float4*)(am2 + ((size_t)(b*256 + j))*8 + 4);
  float4 o0, o1;
  o0.x = msk ? 0.f : __expf(y0.x - n0.x);
  o0.y = msk ? 0.f : __expf(y0.y - n0.y);
  o0.z = msk ? 0.f : __expf(y0.z - n0.z);
  o0.w = msk ? 0.f : __expf(y0.w - n0.w);
  o1.x = msk ? 0.f : __expf(y1.x - n1.x);
  o1.y = msk ? 0.f : __expf(y1.y - n1.y);
  o1.z = msk ? 0.f : __expf(y1.z - n1.z);
  o1.w = msk ? 0.f : __expf(y1.w - n1.w);
  *(float4*)(e2out + p*8) = o0;
  *(float4*)(e2out + p*8 + 4) = o1;

  __syncthreads();
  {
    int hh = tid >> 5, seg = tid & 31;
    int4 v = *(const int4*)((const char*)eb + hh*512 + seg*16);
    *(int4*)(Abuf + (((size_t)(b*136 + 128 + hh)) << 16) + (int)(pos0 & 65535) + seg*8) = v;
  }
}

// ---------------- K4a: pc1[c][i][l] = vb1[pos][c] * e1 (channel transpose) ----------------
__global__ __launch_bounds__(256) void k_prep1(
    const unsigned short* __restrict__ vb1, unsigned short* __restrict__ Abuf)
{
  __shared__ __align__(16) char lds[36864];  // xt [128][272B] + et [8][256B]
  char* xt = lds;
  unsigned short* et = (unsigned short*)(lds + 34816);
  const int tid = threadIdx.x;
  const size_t pos0 = (size_t)blockIdx.x * 128;
  const int b = (int)(pos0 >> 16);
  const int posl0 = (int)(pos0 & 65535);

  if (tid < 128) {
    int hh = tid >> 4, seg = tid & 15;
    int4 v = *(const int4*)(Abuf + (((size_t)(b*136 + 128 + hh)) << 16) + posl0 + seg*8);
    *(int4*)((char*)et + hh*256 + seg*16) = v;
  }
  #pragma unroll
  for (int q = 0; q < 8; ++q) {
    int s = q*256 + tid;
    int rec = s >> 4, g = s & 15;
    int4 v = *(const int4*)(vb1 + (pos0 + rec)*128 + g*8);
    *(int4*)(xt + rec*272 + g*16) = v;
  }
  __syncthreads();
  #pragma unroll
  for (int q = 0; q < 8; ++q) {
    int c = q*16 + (tid & 15);
    int pg = tid >> 4;
    int hh = c >> 4;
    u16x8 t;
    #pragma unroll
    for (int k = 0; k < 8; ++k) {
      int p = pg*8 + k;
      float xv = bf2f(*(const unsigned short*)(xt + p*272 + c*2));
      float ev = bf2f(et[hh*128 + p]);
      t[k] = f2bf(xv * ev);
    }
    *(int4*)(Abuf + (((size_t)(b*136 + c)) << 16) + posl0 + pg*8) = *(int4*)&t;
  }
}

// ---------------- K4b: pc2t[c][j][l] = vb2[(l,j)][c]*e2 ; eb2t[h][j][l] ----------------
// cw split across blockIdx.x: bx = lt*4 + cw  (grid 32 x 16 x 2)
__global__ __launch_bounds__(256) void k_prep2(
    const unsigned short* __restrict__ vb2, const float* __restrict__ e2,
    unsigned short* __restrict__ Bbuf)
{
  __shared__ __align__(16) char lds[49152];  // vt [512][80B] + et [512][16B]
  char* vt = lds;
  unsigned short* et = (unsigned short*)(lds + 40960);  // [rec][8 h] bf16
  const int tid = threadIdx.x;
  const int bx = blockIdx.x, jt = blockIdx.y, b = blockIdx.z;
  const int lt = bx >> 2, cw = bx & 3;
  const int l0 = lt*32, j0 = jt*16;

  #pragma unroll
  for (int q = 0; q < 4; ++q) {
    int s = q*256 + tid;
    int rec = s >> 1, hf = (s & 1)*4;
    int l = rec >> 4, j = rec & 15;
    size_t pos = ((size_t)b << 16) + (size_t)(l0 + l)*256 + (j0 + j);
    float4 ev = *(const float4*)(e2 + pos*8 + hf);
    ushort4 o; o.x = f2bf(ev.x); o.y = f2bf(ev.y); o.z = f2bf(ev.z); o.w = f2bf(ev.w);
    *(ushort4*)(et + rec*8 + hf) = o;
  }

  {
    #pragma unroll
    for (int q = 0; q < 8; ++q) {
      int s = q*256 + tid;
      int rec = s >> 2, g = s & 3;
      int l = rec >> 4, j = rec & 15;
      size_t pos = ((size_t)b << 16) + (size_t)(l0 + l)*256 + (j0 + j);
      int4 v = *(const int4*)(vb2 + pos*128 + cw*32 + g*8);
      *(int4*)(vt + rec*80 + g*16) = v;
    }
    __syncthreads();
    #pragma unroll
    for (int q = 0; q < 8; ++q) {
      int loff = tid & 3, j = (tid >> 2) & 15, cs = tid >> 6;
      int cl = q*4 + cs;
      int c = cw*32 + cl;
      int hh = c >> 4;
      u16x8 t;
      #pragma unroll
      for (int k = 0; k < 8; ++k) {
        int l = loff*8 + k;
        int rec = l*16 + j;
        float xv = bf2f(*(const unsigned short*)(vt + rec*80 + cl*2));
        float ev = bf2f(et[rec*8 + hh]);
        t[k] = f2bf(xv * ev);
      }
      *(int4*)(Bbuf + (((size_t)(b*136 + c)) << 16) + (size_t)(j0 + j)*256 + l0 + loff*8) = *(int4*)&t;
    }
  }
  if (cw == 0) {
    #pragma unroll
    for (int q = 0; q < 2; ++q) {
      int s = q*256 + tid;
      int loff = s & 3, j = (s >> 2) & 15, hh = s >> 6;
      u16x8 t;
      #pragma unroll
      for (int k = 0; k < 8; ++k) {
        int l = loff*8 + k;
        int rec = l*16 + j;
        t[k] = et[rec*8 + hh];
      }
      *(int4*)(Bbuf + (((size_t)(b*136 + 128 + hh)) << 16) + (size_t)(j0 + j)*256 + l0 + loff*8) = *(int4*)&t;
    }
  }
}

// ---------------- K5: batched 256^3 GEMM over 272 channels (tri + denom) ----------------
// XCD-aware block swizzle (proven r15) + swapped-operand MFMA (ushort4 C-stage).
__global__ __launch_bounds__(256) void k_tri_mfma(
    const unsigned short* __restrict__ Ab, const unsigned short* __restrict__ Bb,
    unsigned short* __restrict__ outT)
{
  __shared__ __align__(16) char lds[34816];
  char* lA = lds;
  char* lB = lds + 10240;
  const int tid = threadIdx.x, lane = tid & 63, w = tid >> 6;
  const int bid = blockIdx.x + 2 * blockIdx.y + 4 * blockIdx.z;  // 0..1087
  const int xcd = bid & 7;
  const int slot = bid >> 3;                 // 0..135
  const int ch_all = xcd * 34 + (slot >> 2); // 0..271
  const int tile = slot & 3;
  const int jt = tile & 1, it = tile >> 1;
  const int b = ch_all / 136, ch = ch_all - b*136;
  const size_t mbase = ((size_t)(b*136 + ch)) << 16;
  const int i0 = it*128, j0 = jt*128;
  const int r4 = tid >> 2, g4 = tid & 3;

  const unsigned short* gA0 = Ab + mbase + (size_t)(i0 + r4)*256 + g4*8;
  const unsigned short* gA1 = gA0 + 64*256;
  const unsigned short* gB0 = Bb + mbase + (size_t)(j0 + r4)*256 + g4*8;
  const unsigned short* gB1 = gB0 + 64*256;
  char* sA0 = lA + r4*80 + g4*16;
  char* sA1 = sA0 + 64*80;
  char* sB0 = lB + r4*80 + g4*16;
  char* sB1 = sB0 + 64*80;

  const int wr = w >> 1, wc = w & 1;
  const char* fA = lA + (wr*64 + (lane & 15))*80 + (lane >> 4)*16;
  const char* fB = lB + (wc*64 + (lane & 15))*80 + (lane >> 4)*16;
  const int lg = lane >> 4, lc = lane & 15;

  f32x4 acc[4][4];
  #pragma unroll
  for (int rf = 0; rf < 4; ++rf)
    #pragma unroll
    for (int cf = 0; cf < 4; ++cf) acc[rf][cf] = (f32x4){0.f,0.f,0.f,0.f};

  int4 ra0 = *(const int4*)gA0;
  int4 ra1 = *(const int4*)gA1;
  int4 rb0 = *(const int4*)gB0;
  int4 rb1 = *(const int4*)gB1;

  for (int ks = 0; ks < 8; ++ks) {
    __syncthreads();
    *(int4*)sA0 = ra0; *(int4*)sA1 = ra1;
    *(int4*)sB0 = rb0; *(int4*)sB1 = rb1;
    __syncthreads();
    if (ks < 7) {
      const int off = (ks + 1)*32;
      ra0 = *(const int4*)(gA0 + off);
      ra1 = *(const int4*)(gA1 + off);
      rb0 = *(const int4*)(gB0 + off);
      rb1 = *(const int4*)(gB1 + off);
    }
    bf16x8 af[4], bfv[4];
    #pragma unroll
    for (int rf = 0; rf < 4; ++rf) af[rf] = *(const bf16x8*)(fA + rf*16*80);
    #pragma unroll
    for (int cf = 0; cf < 4; ++cf) bfv[cf] = *(const bf16x8*)(fB + cf*16*80);
    // swapped: D "row regs" follow bfv (j), "col lane" follows af (i)
    #pragma unroll
    for (int rf = 0; rf < 4; ++rf)
      #pragma unroll
      for (int cf = 0; cf < 4; ++cf)
        acc[rf][cf] = __builtin_amdgcn_mfma_f32_16x16x32_bf16(bfv[cf], af[rf], acc[rf][cf], 0, 0, 0);
  }

  __syncthreads();
  #pragma unroll
  for (int rf = 0; rf < 4; ++rf)
    #pragma unroll
    for (int cf = 0; cf < 4; ++cf) {
      int il = wr*64 + rf*16 + lc;
      int jl = wc*64 + cf*16 + 4*lg;
      ushort4 o;
      o.x = f2bf(acc[rf][cf][0]); o.y = f2bf(acc[rf][cf][1]);
      o.z = f2bf(acc[rf][cf][2]); o.w = f2bf(acc[rf][cf][3]);
      *(ushort4*)(lds + il*272 + jl*2) = o;
    }
  __syncthreads();
  #pragma unroll
  for (int q = 0; q < 8; ++q) {
    int row = q*16 + (tid >> 4), seg = tid & 15;
    int4 v = *(const int4*)(lds + row*272 + seg*16);
    *(int4*)(outT + mbase + (size_t)(i0 + row)*256 + j0 + seg*8) = v;
  }
}

// ---------------- K6: x = t/denom ; y = x@wo^T ; hn = bf16(LN1(h + y))
//                  Swapped-operand MFMA (proven r16) + full-wave LN epilogue.
//                  rcp-based division (deterministic, ~1 ulp). ----------------
__global__ __launch_bounds__(512) void k_wo_ln_mfma(
    const unsigned short* __restrict__ tT, const unsigned short* __restrict__ wb,
    const float* __restrict__ h,
    const float* __restrict__ g1, const float* __restrict__ bb1,
    unsigned short* __restrict__ hn)
{
  __shared__ __align__(16) char xb[64 * 256];
  __shared__ __align__(16) char stb[64 * 272];   // bf16 stage [64][136]
  const int tid = threadIdx.x, lane = tid & 63, w = tid >> 6;
  const size_t pos0 = (size_t)blockIdx.x * 64;
  const int b = (int)(pos0 >> 16);
  const int posl0 = (int)(pos0 & 65535);
  const int rh = w >> 2, cq = w & 3;
  const int R = rh * 32;
  const int lg = lane >> 4, lc = lane & 15;

  // ---- stage-in: x = t * rcp(denom) -> xb ----
  #pragma unroll
  for (int it2 = 0; it2 < 2; ++it2) {
    int c = it2*64 + (tid >> 3);
    int poff = (tid & 7)*8;
    u16x8 tv = *(const u16x8*)(tT + (((size_t)(b*136 + c)) << 16) + posl0 + poff);
    u16x8 dv = *(const u16x8*)(tT + (((size_t)(b*136 + 128 + (c >> 4))) << 16) + posl0 + poff);
    int cb = c*2;
    #pragma unroll
    for (int k = 0; k < 8; ++k) {
      float d = bf2f(dv[k]) + 1e-6f;
      float x = bf2f(tv[k]) * __builtin_amdgcn_rcpf(d);
      int p = poff + k;
      int byte = p*256 + ((((cb >> 4) ^ (p & 7))) << 4) + (cb & 15);
      *(unsigned short*)(xb + byte) = f2bf(x);
    }
  }
  __syncthreads();

  // ---- GEMM (swapped): y = x @ wo^T -> stb via ushort4 ----
  {
    const unsigned short* wbo = wb + 2 * 16384;
    f32x4 acc[2][2];          // [xhalf][cf]
    #pragma unroll
    for (int xh = 0; xh < 2; ++xh)
      #pragma unroll
      for (int cf = 0; cf < 2; ++cf) acc[xh][cf] = (f32x4){0.f,0.f,0.f,0.f};
    #pragma unroll
    for (int ks = 0; ks < 4; ++ks) {
      bf16x8 a0  = lds_afrag(xb, R,      ks * 32, lane);
      bf16x8 a1f = lds_afrag(xb, R + 16, ks * 32, lane);
      #pragma unroll
      for (int cf = 0; cf < 2; ++cf) {
        bf16x8 bf = wb_frag(wbo, cq * 2 + cf, ks, lane);
        acc[0][cf] = __builtin_amdgcn_mfma_f32_16x16x32_bf16(bf, a0,  acc[0][cf], 0, 0, 0);
        acc[1][cf] = __builtin_amdgcn_mfma_f32_16x16x32_bf16(bf, a1f, acc[1][cf], 0, 0, 0);
      }
    }
    #pragma unroll
    for (int xh = 0; xh < 2; ++xh)
      #pragma unroll
      for (int cf = 0; cf < 2; ++cf) {
        int row = R + xh*16 + lc;
        int colb = cq*32 + cf*16 + 4*lg;
        ushort4 o;
        o.x = f2bf(acc[xh][cf][0]); o.y = f2bf(acc[xh][cf][1]);
        o.z = f2bf(acc[xh][cf][2]); o.w = f2bf(acc[xh][cf][3]);
        *(ushort4*)(stb + row*272 + colb*2) = o;
      }
  }
  __syncthreads();

  // ---- LN1 epilogue: full-wave pattern (proven r6/r11/r13/r14/r15/r16) ----
  const float ga = g1[lane], gb = g1[64 + lane];
  const float ba = bb1[lane], bbv = bb1[64 + lane];
  for (int rr = 0; rr < 8; ++rr) {
    int row = w * 8 + rr;
    float y0 = bf2f(*(const unsigned short*)(stb + row*272 + lane*2));
    float y1 = bf2f(*(const unsigned short*)(stb + row*272 + (64 + lane)*2));
    float r0 = h[(pos0 + row) * 128 + lane] + y0;
    float r1 = h[(pos0 + row) * 128 + 64 + lane] + y1;
    float s = r0 + r1, sq = r0*r0 + r1*r1;
    #pragma unroll
    for (int m = 1; m < 64; m <<= 1) { s += __shfl_xor(s, m); sq += __shfl_xor(sq, m); }
    float mu = s * (1.f/128.f);
    float var = sq * (1.f/128.f) - mu*mu;
    float rstd = rsqrtf(var + 1e-5f);
    hn[(pos0 + row) * 128 + lane]      = f2bf((r0 - mu) * rstd * ga + ba);
    hn[(pos0 + row) * 128 + 64 + lane] = f2bf((r1 - mu) * rstd * gb + bbv);
  }
}

// ---------------- K7: FFN(silu) + residual + LN2 -> out (swapped MFMA, rcp silu) ----------------
__global__ __launch_bounds__(512) void k_ffn_ln_mfma(
    const unsigned short* __restrict__ hnp, const unsigned short* __restrict__ wb,
    const float* __restrict__ bias1, const float* __restrict__ bias2,
    const float* __restrict__ g2, const float* __restrict__ b2v,
    float* __restrict__ out)
{
  __shared__ __align__(16) char xb[64 * 256];       // x then u (bf16 swizzled)
  __shared__ __align__(16) char stb[64 * 272];      // bf16 stage [64][136]
  const int tid = threadIdx.x, lane = tid & 63, w = tid >> 6;
  const size_t pos0 = (size_t)blockIdx.x * 64;
  const int rh = w >> 2, cq = w & 3;
  const int R = rh * 32;
  const int lg = lane >> 4, lc = lane & 15;
  const unsigned short* wb1 = wb + 3 * 16384;
  const unsigned short* wb2 = wb + 4 * 16384;

  bf16x8 bf1[2][4];
  #pragma unroll
  for (int cf = 0; cf < 2; ++cf)
    #pragma unroll
    for (int ks = 0; ks < 4; ++ks)
      bf1[cf][ks] = wb_frag(wb1, cq * 2 + cf, ks, lane);

  #pragma unroll
  for (int q = 0; q < 2; ++q) {
    int s = q*512 + tid;
    int row = s >> 4, g = s & 15;
    int4 v = *(const int4*)(hnp + (pos0 + row)*128 + g*8);
    *(int4*)(xb + row*256 + (((g ^ (row & 7))) << 4)) = v;
  }
  __syncthreads();

  // ---- GEMM1 (swapped): acc[xh][cf], u = silu(acc + b1) via rcp -> xb ----
  f32x4 acc[2][2];
  #pragma unroll
  for (int xh = 0; xh < 2; ++xh)
    #pragma unroll
    for (int cf = 0; cf < 2; ++cf) acc[xh][cf] = (f32x4){0.f,0.f,0.f,0.f};

  #pragma unroll
  for (int ks = 0; ks < 4; ++ks) {
    bf16x8 a0  = lds_afrag(xb, R,      ks * 32, lane);
    bf16x8 a1f = lds_afrag(xb, R + 16, ks * 32, lane);
    #pragma unroll
    for (int cf = 0; cf < 2; ++cf) {
      acc[0][cf] = __builtin_amdgcn_mfma_f32_16x16x32_bf16(bf1[cf][ks], a0,  acc[0][cf], 0, 0, 0);
      acc[1][cf] = __builtin_amdgcn_mfma_f32_16x16x32_bf16(bf1[cf][ks], a1f, acc[1][cf], 0, 0, 0);
    }
  }
  __syncthreads();

  {
    #pragma unroll
    for (int xh = 0; xh < 2; ++xh)
      #pragma unroll
      for (int cf = 0; cf < 2; ++cf) {
        int row = R + xh*16 + lc;
        int colb = cq*32 + cf*16 + 4*lg;
        float4 bv = *(const float4*)&bias1[colb];
        float s0 = acc[xh][cf][0] + bv.x;
        float s1 = acc[xh][cf][1] + bv.y;
        float s2 = acc[xh][cf][2] + bv.z;
        float s3 = acc[xh][cf][3] + bv.w;
        float u0 = s0 * __builtin_amdgcn_rcpf(1.f + __expf(-s0));
        float u1 = s1 * __builtin_amdgcn_rcpf(1.f + __expf(-s1));
        float u2 = s2 * __builtin_amdgcn_rcpf(1.f + __expf(-s2));
        float u3 = s3 * __builtin_amdgcn_rcpf(1.f + __expf(-s3));
        lds_store4bf(xb, row, colb*2, u0, u1, u2, u3);
      }
  }
  __syncthreads();

  // ---- GEMM3 (swapped): y2 = u @ w2^T + b2 -> stb via ushort4 ----
  f32x4 acc2[2][2];
  #pragma unroll
  for (int xh = 0; xh < 2; ++xh)
    #pragma unroll
    for (int cf = 0; cf < 2; ++cf) acc2[xh][cf] = (f32x4){0.f,0.f,0.f,0.f};

  #pragma unroll
  for (int ks = 0; ks < 4; ++ks) {
    bf16x8 b0 = wb_frag(wb2, cq * 2,     ks, lane);
    bf16x8 b1 = wb_frag(wb2, cq * 2 + 1, ks, lane);
    bf16x8 a0  = lds_afrag(xb, R,      ks * 32, lane);
    bf16x8 a1f = lds_afrag(xb, R + 16, ks * 32, lane);
    acc2[0][0] = __builtin_amdgcn_mfma_f32_16x16x32_bf16(b0, a0,  acc2[0][0], 0, 0, 0);
    acc2[0][1] = __builtin_amdgcn_mfma_f32_16x16x32_bf16(b1, a0,  acc2[0][1], 0, 0, 0);
    acc2[1][0] = __builtin_amdgcn_mfma_f32_16x16x32_bf16(b0, a1f, acc2[1][0], 0, 0, 0);
    acc2[1][1] = __builtin_amdgcn_mfma_f32_16x16x32_bf16(b1, a1f, acc2[1][1], 0, 0, 0);
  }

  {
    #pragma unroll
    for (int xh = 0; xh < 2; ++xh)
      #pragma unroll
      for (int cf = 0; cf < 2; ++cf) {
        int row = R + xh*16 + lc;
        int colb = cq*32 + cf*16 + 4*lg;
        float4 bv = *(const float4*)&bias2[colb];
        ushort4 o;
        o.x = f2bf(acc2[xh][cf][0] + bv.x);
        o.y = f2bf(acc2[xh][cf][1] + bv.y);
        o.z = f2bf(acc2[xh][cf][2] + bv.z);
        o.w = f2bf(acc2[xh][cf][3] + bv.w);
        *(ushort4*)(stb + row*272 + colb*2) = o;
      }
  }
  __syncthreads();

  // ---- LN2 epilogue: full-wave pattern (proven) ----
  const float ga = g2[lane], gb = g2[64 + lane];
  const float ba = b2v[lane], bbv = b2v[64 + lane];
  for (int rr = 0; rr < 8; ++rr) {
    int row = w * 8 + rr;
    float y0 = bf2f(*(const unsigned short*)(stb + row*272 + lane*2));
    float y1 = bf2f(*(const unsigned short*)(stb + row*272 + (64 + lane)*2));
    float r0 = bf2f(hnp[(pos0 + row) * 128 + lane]) + y0;
    float r1 = bf2f(hnp[(pos0 + row) * 128 + 64 + lane]) + y1;
    float s = r0 + r1, sq = r0*r0 + r1*r1;
    #pragma unroll
    for (int m = 1; m < 64; m <<= 1) { s += __shfl_xor(s, m); sq += __shfl_xor(sq, m); }
    float mu = s * (1.f/128.f);
    float var = sq * (1.f/128.f) - mu*mu;
    float rstd = rsqrtf(var + 1e-5f);
    out[(pos0 + row) * 128 + lane]      = (r0 - mu) * rstd * ga + ba;
    out[(pos0 + row) * 128 + 64 + lane] = (r1 - mu) * rstd * gb + bbv;
  }
}

extern "C" void kernel_launch(void* const* d_in, const int* in_sizes, int n_in,
                              void* d_out, int out_size, void* d_ws, size_t ws_size,
                              hipStream_t stream)
{
  const float* h    = (const float*)d_in[0];
  const void*  mask = d_in[1];
  const float* wa1  = (const float*)d_in[2];
  const float* wa2  = (const float*)d_in[3];
  const float* wv1  = (const float*)d_in[4];
  const float* wv2  = (const float*)d_in[5];
  const float* wo   = (const float*)d_in[6];
  const float* ln1s = (const float*)d_in[7];
  const float* ln1b = (const float*)d_in[8];
  const float* ln2s = (const float*)d_in[9];
  const float* ln2b = (const float*)d_in[10];
  const float* wu1  = (const float*)d_in[11];
  const float* bu1  = (const float*)d_in[12];
  const float* wu2  = (const float*)d_in[13];
  const float* bu2  = (const float*)d_in[14];

  char* ws = (char*)d_ws;
  const size_t MB = 1024*1024;
  unsigned short* vb1   = (unsigned short*)(ws + 0);        // 32 MB
  unsigned short* tbufT = (unsigned short*)(ws + 0);        // 35.7 MB (aliases vb1)
  unsigned short* vb2   = (unsigned short*)(ws + 36*MB);    // 32 MB
  unsigned short* hn    = (unsigned short*)(ws + 36*MB);    // 32 MB (aliases vb2)
  unsigned short* Bbuf  = (unsigned short*)(ws + 68*MB);    // 35.7 MB
  float* a1  = (float*)(ws + 104*MB);                       // 4 MB
  float* a2  = (float*)(ws + 108*MB);                       // 4 MB
  float* e2  = (float*)(ws + 112*MB);                       // 4 MB
  float* am1 = (float*)(ws + 116*MB);
  float* am2 = (float*)(ws + 116*MB + 16384);
  int*   flg = (int*)  (ws + 116*MB + 32768);
  int*   part= (int*)  (ws + 116*MB + 65536);               // 128 ints
  unsigned short* wb = (unsigned short*)(ws + 117*MB);      // 84 KB frag-major weights
  unsigned short* Abuf = (unsigned short*)d_out;            // 35.7 MB in 64 MB out

  k_maskpart<<<128, 256, 0, stream>>>((const unsigned int*)mask, part);
  k_maskred<<<1, 128, 0, stream>>>(part, flg);
  k_wconv<<<6, 256, 0, stream>>>(wv1, wv2, wo, wu1, wu2, wa1, wa2, wb);
  k_proj_mfma<<<2048, 512, 0, stream>>>(h, wb, a1, a2, vb1, vb2);
  k_rowmax<<<1024, 64, 0, stream>>>(a1, a2, am1, am2);
  k_e<<<512, 256, 0, stream>>>(mask, flg, a1, a2, am1, am2, e2, Abuf);
  k_prep1<<<1024, 256, 0, stream>>>(vb1, Abuf);
  k_prep2<<<dim3(32,16,2), 256, 0, stream>>>(vb2, e2, Bbuf);
  k_tri_mfma<<<dim3(2,2,272), 256, 0, stream>>>(Abuf, Bbuf, tbufT);
  k_wo_ln_mfma<<<2048, 512, 0, stream>>>(tbufT, wb, h, ln1s, ln1b, hn);
  k_ffn_ln_mfma<<<2048, 512, 0, stream>>>(hn, wb, bu1, bu2, ln2s, ln2b, (float*)d_out);
}